// Round 10
// baseline (177.921 us; speedup 1.0000x reference)
//
#include <hip/hip_runtime.h>
#include <hip/hip_bf16.h>

#define NUM_C 1000
#define DIM   128
#define MM    64
#define BB    64
#define LL    512
#define NROWS (BB * LL)   // 32768

typedef unsigned short u16;
typedef unsigned int   u32;
typedef short bfrag __attribute__((ext_vector_type(8)));   // 8 bf16 (4 VGPRs)
typedef float f32x4 __attribute__((ext_vector_type(4)));   // MFMA acc

__device__ __forceinline__ float sigmoidf_fast(float x) { return 1.f / (1.f + __expf(-x)); }
__device__ __forceinline__ float tanhf_fast(float x) { return 1.f - 2.f / (__expf(2.f * x) + 1.f); }

__device__ __forceinline__ u16 f2bf(float x) {            // RNE f32->bf16 bits
    u32 u = __float_as_uint(x);
    return (u16)((u + 0x7FFFu + ((u >> 16) & 1u)) >> 16);
}
__device__ __forceinline__ float bf2f(u16 h) { return __uint_as_float(((u32)h) << 16); }

// DPP quad_perm swaps + row ops (VALU-only)
__device__ __forceinline__ float quad_swap1(float x) {    // lane ^ 1
    return __int_as_float(__builtin_amdgcn_mov_dpp(__float_as_int(x), 0xB1, 0xF, 0xF, true));
}
__device__ __forceinline__ float quad_swap2(float x) {    // lane ^ 2
    return __int_as_float(__builtin_amdgcn_mov_dpp(__float_as_int(x), 0x4E, 0xF, 0xF, true));
}
// ROW_HALF_MIRROR (0x141): within each aligned 8-lane half-row, pos j <-> 7-j.
// Direction-unambiguous complement-quad exchange (r21's row_ror4 failed:
// ROW_ROR direction made position 0 receive the OTHER half-row's quad).
__device__ __forceinline__ float half_mirror(float x) {
    return __int_as_float(__builtin_amdgcn_mov_dpp(__float_as_int(x), 0x141, 0xF, 0xF, true));
}
__device__ __forceinline__ float row_ror4(float x) {
    return __int_as_float(__builtin_amdgcn_mov_dpp(__float_as_int(x), 0x124, 0xF, 0xF, true));
}
__device__ __forceinline__ float row_ror8(float x) {
    return __int_as_float(__builtin_amdgcn_mov_dpp(__float_as_int(x), 0x128, 0xF, 0xF, true));
}

// async global->LDS DMA, 16B per lane, LDS dest = wave-uniform base + lane*16
__device__ __forceinline__ void ld16(const void* g, void* l) {
    __builtin_amdgcn_global_load_lds(
        (const __attribute__((address_space(1))) unsigned int*)g,
        (__attribute__((address_space(3))) unsigned int*)l, 16, 0, 0);
}

// ---------------------------------------------------------------------------
// Prep: B-side weights as bf16 hi/lo ([n][k] transposed); A-side embeddings
// Ek/Ev pre-converted to bf16 hi ONCE (removes per-row conversion in kAB/kD).
// ---------------------------------------------------------------------------
__global__ __launch_bounds__(256) void kP(const float* __restrict__ We,
                                          const float* __restrict__ Wa,
                                          const float* __restrict__ Wf,
                                          const float* __restrict__ Mk,
                                          const float* __restrict__ Ek,
                                          const float* __restrict__ Ev,
                                          u16* weT_hi, u16* weT_lo,
                                          u16* waT_hi, u16* waT_lo,
                                          u16* wfT_hi, u16* wfT_lo,
                                          u16* mkT_hi, u16* mkT_lo,
                                          u16* ekbf, u16* evbf) {
    int idx = blockIdx.x * 256 + threadIdx.x;   // 0..32767
    if (idx < 128 * 128) {
        int n = idx >> 7, k = idx & 127;
        float we = We[k * DIM + n];
        u16 h = f2bf(we);
        weT_hi[idx] = h; weT_lo[idx] = f2bf(we - bf2f(h));
        float wa = Wa[k * DIM + n];
        u16 h2 = f2bf(wa);
        waT_hi[idx] = h2; waT_lo[idx] = f2bf(wa - bf2f(h2));
    }
    if (idx < 64 * 128) {
        float mk = Mk[idx];
        u16 h = f2bf(mk);
        mkT_hi[idx] = h; mkT_lo[idx] = f2bf(mk - bf2f(h));
    }
    {
        int n = idx >> 8, k = idx & 255;
        float wf = Wf[k * DIM + n];
        u16 h = f2bf(wf);
        wfT_hi[idx] = h; wfT_lo[idx] = f2bf(wf - bf2f(h));
    }
    for (int i = idx; i < NUM_C * DIM; i += 32768) ekbf[i] = f2bf(Ek[i]);
    for (int i = idx; i < 2 * NUM_C * DIM; i += 32768) evbf[i] = f2bf(Ev[i]);
}

// ---------------------------------------------------------------------------
// Fused kAB (MFMA, A=bf16-hi only, B=hi+lo). Blocks [0,512): kA role.
// Blocks [512,1024): kB role. 64 rows/block; staging = pure u16 gather.
// f32 outputs (r15/r20 interface).
// ---------------------------------------------------------------------------
__global__ __launch_bounds__(256) void kAB(const int* __restrict__ q,
                                           const int* __restrict__ r,
                                           const u16* __restrict__ ekbf,
                                           const u16* __restrict__ evbf,
                                           const u16* __restrict__ mkT_hi, const u16* __restrict__ mkT_lo,
                                           const u16* __restrict__ weT_hi, const u16* __restrict__ weT_lo,
                                           const u16* __restrict__ waT_hi, const u16* __restrict__ waT_lo,
                                           const float* __restrict__ be, const float* __restrict__ ba,
                                           float* __restrict__ w_out,
                                           float2* __restrict__ ea_out) {
    __shared__ __align__(16) u16 shi[4][16][136];
    __shared__ float slab[4][64];
    const int tid = threadIdx.x;
    const int lane = tid & 63;
    const int wv = tid >> 6;
    const int nloc = lane & 15;
    const int quad = lane >> 4;

    if (blockIdx.x < 512) {
        // ---------------- kA role ----------------
        const int base = blockIdx.x * 64;
        {   // stage k = ekbf[q] (already bf16)
            const int row_l = tid >> 2;
            const int rts = row_l >> 4, ms = row_l & 15;
            const int d0 = (tid & 3) * 32;
            const u16* src = ekbf + (size_t)q[base + row_l] * DIM + d0;
            #pragma unroll
            for (int c8 = 0; c8 < 4; ++c8)
                *reinterpret_cast<bfrag*>(&shi[rts][ms][d0 + c8 * 8]) =
                    *reinterpret_cast<const bfrag*>(src + c8 * 8);
        }
        __syncthreads();

        const int n = wv * 16 + nloc;      // m index
        bfrag Bh[4], Bl[4];
        #pragma unroll
        for (int kc = 0; kc < 4; ++kc) {
            const int ko = kc * 32 + quad * 8;
            Bh[kc] = *reinterpret_cast<const bfrag*>(mkT_hi + n * DIM + ko);
            Bl[kc] = *reinterpret_cast<const bfrag*>(mkT_lo + n * DIM + ko);
        }

        f32x4 acc[4];
        #pragma unroll
        for (int t = 0; t < 4; ++t) acc[t] = 0.f;

        #pragma unroll
        for (int rt = 0; rt < 4; ++rt) {
            #pragma unroll
            for (int kc = 0; kc < 4; ++kc) {
                const int ko = kc * 32 + quad * 8;
                bfrag Ah = *reinterpret_cast<const bfrag*>(&shi[rt][nloc][ko]);
                acc[rt] = __builtin_amdgcn_mfma_f32_16x16x32_bf16(Ah, Bh[kc], acc[rt], 0, 0, 0);
                acc[rt] = __builtin_amdgcn_mfma_f32_16x16x32_bf16(Ah, Bl[kc], acc[rt], 0, 0, 0);
            }
        }

        float ex[4][4];
        #pragma unroll
        for (int rt = 0; rt < 4; ++rt) {
            #pragma unroll
            for (int rg = 0; rg < 4; ++rg) {
                float e = __expf(acc[rt][rg]);
                ex[rt][rg] = e;
                float s = e;
                s += __shfl_xor(s, 1);
                s += __shfl_xor(s, 2);
                s += __shfl_xor(s, 4);
                s += __shfl_xor(s, 8);
                if (nloc == 0) slab[wv][rt * 16 + quad * 4 + rg] = s;
            }
        }
        __syncthreads();

        #pragma unroll
        for (int rt = 0; rt < 4; ++rt) {
            #pragma unroll
            for (int rg = 0; rg < 4; ++rg) {
                const int row = rt * 16 + quad * 4 + rg;
                float tot = slab[0][row] + slab[1][row] + slab[2][row] + slab[3][row];
                w_out[(size_t)(base + row) * MM + n] = ex[rt][rg] / tot;
            }
        }
    } else {
        // ---------------- kB role ----------------
        const int base = (blockIdx.x - 512) * 64;
        {   // stage v = evbf[x] (already bf16)
            const int row_l = tid >> 2;
            const int rts = row_l >> 4, ms = row_l & 15;
            const int d0 = (tid & 3) * 32;
            const int row = base + row_l;
            const int x = q[row] + NUM_C * r[row];
            const u16* src = evbf + (size_t)x * DIM + d0;
            #pragma unroll
            for (int c8 = 0; c8 < 4; ++c8)
                *reinterpret_cast<bfrag*>(&shi[rts][ms][d0 + c8 * 8]) =
                    *reinterpret_cast<const bfrag*>(src + c8 * 8);
        }
        __syncthreads();

        #pragma unroll
        for (int dt = 0; dt < 2; ++dt) {
            const int n = (wv * 2 + dt) * 16 + nloc;
            bfrag Beh[4], Bel[4], Bah[4], Bal[4];
            #pragma unroll
            for (int kc = 0; kc < 4; ++kc) {
                const int ko = kc * 32 + quad * 8;
                Beh[kc] = *reinterpret_cast<const bfrag*>(weT_hi + n * DIM + ko);
                Bel[kc] = *reinterpret_cast<const bfrag*>(weT_lo + n * DIM + ko);
                Bah[kc] = *reinterpret_cast<const bfrag*>(waT_hi + n * DIM + ko);
                Bal[kc] = *reinterpret_cast<const bfrag*>(waT_lo + n * DIM + ko);
            }
            f32x4 acc_e[4], acc_a[4];
            #pragma unroll
            for (int t = 0; t < 4; ++t) { acc_e[t] = 0.f; acc_a[t] = 0.f; }

            #pragma unroll
            for (int rt = 0; rt < 4; ++rt) {
                #pragma unroll
                for (int kc = 0; kc < 4; ++kc) {
                    const int ko = kc * 32 + quad * 8;
                    bfrag Ah = *reinterpret_cast<const bfrag*>(&shi[rt][nloc][ko]);
                    acc_e[rt] = __builtin_amdgcn_mfma_f32_16x16x32_bf16(Ah, Beh[kc], acc_e[rt], 0, 0, 0);
                    acc_a[rt] = __builtin_amdgcn_mfma_f32_16x16x32_bf16(Ah, Bah[kc], acc_a[rt], 0, 0, 0);
                    acc_e[rt] = __builtin_amdgcn_mfma_f32_16x16x32_bf16(Ah, Bel[kc], acc_e[rt], 0, 0, 0);
                    acc_a[rt] = __builtin_amdgcn_mfma_f32_16x16x32_bf16(Ah, Bal[kc], acc_a[rt], 0, 0, 0);
                }
            }
            const float bev = be[n], bav = ba[n];
            #pragma unroll
            for (int rt = 0; rt < 4; ++rt) {
                #pragma unroll
                for (int rg = 0; rg < 4; ++rg) {
                    const int row = base + rt * 16 + quad * 4 + rg;
                    float2 ea;
                    ea.x = sigmoidf_fast(acc_e[rt][rg] + bev);
                    ea.y = tanhf_fast(acc_a[rt][rg] + bav);
                    ea_out[(size_t)row * DIM + n] = ea;
                }
            }
        }
    }
}

// ---------------------------------------------------------------------------
// Kernel C (r22 = r21 + reduce fix): 8-m-per-thread mapping. lane = dlo*8+p
// (p=0..7 m-group, dlo=0..7 d). w8 via 2x ds_read_b128 (8-lane broadcast,
// 2-way alias = free), 8 Mv regs. Reduce over the aligned 8-lane half-row:
// quad_swap1 (xor1) -> quad_swap2 (xor2) -> HALF_MIRROR (pos j<->7-j, the
// complement-quad exchange; r21's row_ror4 was direction-dependent and
// summed across d-groups -> absmax fail). Stages 2-3+store deferred one
// step to keep the chain off the critical path. ~39 inst per 8 m*d vs 56
// (-30%). Grid (4,64) = 1 block/CU, 4 waves/CU. launch_bounds(256,1).
// ---------------------------------------------------------------------------
__device__ __forceinline__ void scan32(const float* wb, const float2* eab,
                                       int p8, int jcol, int p, int t0,
                                       float (&Mv)[8], float* rp) {
    float4 wqa[4], wqb[4];
    float2 eq[4];
    #pragma unroll
    for (int u = 0; u < 4; ++u) {
        wqa[u] = *reinterpret_cast<const float4*>(wb + u * 64 + p8);
        wqb[u] = *reinterpret_cast<const float4*>(wb + u * 64 + p8 + 4);
        eq[u]  = eab[u * 32 + jcol];
    }
    float prev = 0.f;   // step u-1 partial, stage1 applied
    #pragma unroll
    for (int u = 0; u < 32; ++u) {
        float4 wa = wqa[u & 3], wb4 = wqb[u & 3];
        float2 ea = eq[u & 3];
        if (u + 4 < 32) {
            wqa[u & 3] = *reinterpret_cast<const float4*>(wb + (u + 4) * 64 + p8);
            wqb[u & 3] = *reinterpret_cast<const float4*>(wb + (u + 4) * 64 + p8 + 4);
            eq[u & 3]  = eab[(u + 4) * 32 + jcol];
        }
        // finish previous step's reduce (stages 2,3) + store
        if (u >= 1) {
            float f = prev;
            f += quad_swap2(f);
            f += half_mirror(f);
            if (p == 0) rp[(size_t)(t0 + u - 1) * DIM] = f;
        }
        float e_c = ea.x, a_c = ea.y;
        float o0 = Mv[0], o1 = Mv[1], o2 = Mv[2], o3 = Mv[3];
        float o4 = Mv[4], o5 = Mv[5], o6 = Mv[6], o7 = Mv[7];
        float part0 = wa.x * o0;
        part0 = fmaf(wa.y, o1, part0);
        part0 = fmaf(wa.z, o2, part0);
        part0 = fmaf(wa.w, o3, part0);
        float part1 = wb4.x * o4;
        part1 = fmaf(wb4.y, o5, part1);
        part1 = fmaf(wb4.z, o6, part1);
        part1 = fmaf(wb4.w, o7, part1);
        Mv[0] = fmaf(wa.x,  fmaf(-o0, e_c, a_c), o0);
        Mv[1] = fmaf(wa.y,  fmaf(-o1, e_c, a_c), o1);
        Mv[2] = fmaf(wa.z,  fmaf(-o2, e_c, a_c), o2);
        Mv[3] = fmaf(wa.w,  fmaf(-o3, e_c, a_c), o3);
        Mv[4] = fmaf(wb4.x, fmaf(-o4, e_c, a_c), o4);
        Mv[5] = fmaf(wb4.y, fmaf(-o5, e_c, a_c), o5);
        Mv[6] = fmaf(wb4.z, fmaf(-o6, e_c, a_c), o6);
        Mv[7] = fmaf(wb4.w, fmaf(-o7, e_c, a_c), o7);
        float part = part0 + part1;
        part += quad_swap1(part);     // stage 1 only; rest next iteration
        prev = part;
    }
    {   // flush step 31: stages 2,3 + store
        float f = prev;
        f += quad_swap2(f);
        f += half_mirror(f);
        if (p == 0) rp[(size_t)(t0 + 31) * DIM] = f;
    }
}

__global__ __launch_bounds__(256, 1) void kC(const float* __restrict__ Mv0,
                                             const float* __restrict__ w_in,
                                             const float2* __restrict__ ea_in,
                                             float* __restrict__ rd) {
    __shared__ __align__(16) float  wlds[2][32][64];    // 16 KB
    __shared__ __align__(16) float2 ealds[2][32][32];   // 16 KB
    const int tid  = threadIdx.x;
    const int lane = tid & 63;
    const int wv   = tid >> 6;        // 0..3
    const int p    = lane & 7;        // m-group 0..7 (8 m each)
    const int dlo  = lane >> 3;       // 0..7: d within wave
    const int jcol = wv * 8 + dlo;    // 0..31: d within block slice
    const int ds   = blockIdx.x;      // d-chunk 0..3
    const int b    = blockIdx.y;      // batch
    const int d    = ds * 32 + jcol;
    const int p8   = p * 8;

    const char* wsrc  = (const char*)(w_in + (size_t)b * LL * MM);
    const char* easrc = (const char*)(ea_in + (size_t)b * LL * DIM + ds * 32);
    float* rp = rd + (size_t)b * LL * DIM + d;

    auto dma = [&](int c, int bufi) {
        const char* wt = wsrc + (size_t)c * 8192;         // w tile: 32x64 f32 = 8 KB
        char* wl = (char*)&wlds[bufi][0][0];
        char* el = (char*)&ealds[bufi][0][0];
        const int off = tid * 16;                         // 0..4095
        ld16(wt + off, wl + off);
        ld16(wt + 4096 + off, wl + 4096 + off);
        // ea tile: 32 rows x 32 d x 8 B = 8 KB; 256 B per row, global row
        // stride DIM*8 = 1024 B; 16 lanes per row, 2 rounds of 16 rows.
        const int er = tid >> 4, ec = (tid & 15) * 16;
        ld16(easrc + (size_t)(c * 32 + er) * (DIM * 8) + ec, el + off);
        ld16(easrc + (size_t)(c * 32 + 16 + er) * (DIM * 8) + ec, el + 4096 + off);
    };

    dma(0, 0);

    float Mv[8];
    #pragma unroll
    for (int j = 0; j < 8; ++j)
        Mv[j] = Mv0[(p8 + j) * DIM + d];

    __builtin_amdgcn_s_waitcnt(0x0F70);   // vmcnt(0): tile-0 DMA + Mv loads done
    __syncthreads();

    int buf = 0;
    for (int c = 0; c < LL / 32; ++c) {
        if (c + 1 < LL / 32) dma(c + 1, buf ^ 1);
        scan32(&wlds[buf][0][0], &ealds[buf][0][0], p8, jcol, p, c * 32, Mv, rp);
        if (c + 1 < LL / 32) {
            __builtin_amdgcn_s_waitcnt(0x8F70);   // vmcnt(32): 4 DMAs retired, stores may fly
            __syncthreads();
            buf ^= 1;
        }
    }
}

// ---------------------------------------------------------------------------
// Kernel D (MFMA, A=hi only): f = tanh([rd,k]@Wf+bf); p = sigmoid(f@Wp+bp).
// 64 rows/block; rd staged via f2bf (hi), Ek gathered pre-converted.
// ---------------------------------------------------------------------------
__global__ __launch_bounds__(256) void kD(const int* __restrict__ q,
                                          const u16* __restrict__ ekbf,
                                          const u16* __restrict__ wfT_hi, const u16* __restrict__ wfT_lo,
                                          const float* __restrict__ bfv,
                                          const float* __restrict__ Wp, const float* __restrict__ bp,
                                          const float* __restrict__ rd,
                                          float* __restrict__ out) {
    __shared__ __align__(16) u16 xhi[4][16][264];   // 33792 B (fbuf overlays exactly)
    __shared__ float sred[64][4];
    const int tid = threadIdx.x;
    const int base = blockIdx.x * 64;
    const int row_l = tid >> 2;
    const int rts = row_l >> 4, ms = row_l & 15;
    const int d0 = (tid & 3) * 32;
    const int row = base + row_l;

    {   // x[:, 0:128) = rd -> bf16 hi
        const float* src = rd + (size_t)row * DIM + d0;
        #pragma unroll
        for (int c8 = 0; c8 < 4; ++c8) {
            float4 f0 = *reinterpret_cast<const float4*>(src + c8 * 8);
            float4 f1 = *reinterpret_cast<const float4*>(src + c8 * 8 + 4);
            float xs[8] = {f0.x, f0.y, f0.z, f0.w, f1.x, f1.y, f1.z, f1.w};
            bfrag h;
            #pragma unroll
            for (int j = 0; j < 8; ++j) h[j] = (short)f2bf(xs[j]);
            *reinterpret_cast<bfrag*>(&xhi[rts][ms][d0 + c8 * 8]) = h;
        }
    }
    {   // x[:, 128:256) = ekbf[q[row]] (already bf16)
        const u16* src = ekbf + (size_t)q[row] * DIM + d0;
        #pragma unroll
        for (int c8 = 0; c8 < 4; ++c8)
            *reinterpret_cast<bfrag*>(&xhi[rts][ms][128 + d0 + c8 * 8]) =
                *reinterpret_cast<const bfrag*>(src + c8 * 8);
    }
    __syncthreads();

    const int lane = tid & 63;
    const int wv = tid >> 6;
    const int nloc = lane & 15;
    const int quad = lane >> 4;
    float* fbuf = reinterpret_cast<float*>(&xhi[0][0][0]);   // overlay after sync

    f32x4 acc[2][4];
    #pragma unroll
    for (int dt = 0; dt < 2; ++dt)
        #pragma unroll
        for (int t = 0; t < 4; ++t) acc[dt][t] = 0.f;

    #pragma unroll
    for (int dt = 0; dt < 2; ++dt) {
        const int n = (wv * 2 + dt) * 16 + nloc;
        bfrag Bh[8], Bl[8];
        #pragma unroll
        for (int kc = 0; kc < 8; ++kc) {
            const int ko = kc * 32 + quad * 8;
            Bh[kc] = *reinterpret_cast<const bfrag*>(wfT_hi + n * 256 + ko);
            Bl[kc] = *reinterpret_cast<const bfrag*>(wfT_lo + n * 256 + ko);
        }
        #pragma unroll
        for (int rt = 0; rt < 4; ++rt) {
            #pragma unroll
            for (int kc = 0; kc < 8; ++kc) {
                const int ko = kc * 32 + quad * 8;
                bfrag Ah = *reinterpret_cast<const bfrag*>(&xhi[rt][nloc][ko]);
                acc[dt][rt] = __builtin_amdgcn_mfma_f32_16x16x32_bf16(Ah, Bh[kc], acc[dt][rt], 0, 0, 0);
                acc[dt][rt] = __builtin_amdgcn_mfma_f32_16x16x32_bf16(Ah, Bl[kc], acc[dt][rt], 0, 0, 0);
            }
        }
    }
    __syncthreads();   // LDS x reads done before fbuf overlay

    #pragma unroll
    for (int dt = 0; dt < 2; ++dt) {
        const int n = (wv * 2 + dt) * 16 + nloc;
        const float bfn = bfv[n], wpn = Wp[n];
        #pragma unroll
        for (int rt = 0; rt < 4; ++rt)
            #pragma unroll
            for (int rg = 0; rg < 4; ++rg)
                fbuf[(rt * 16 + quad * 4 + rg) * 132 + n] = tanhf_fast(acc[dt][rt][rg] + bfn) * wpn;
    }
    __syncthreads();

    {
        float s = 0.f;
        const int c = tid & 3;
        #pragma unroll
        for (int k = 0; k < 32; ++k) s += fbuf[row_l * 132 + c * 32 + k];
        sred[row_l][c] = s;
    }
    __syncthreads();
    if (tid < 64)
        out[base + tid] = sigmoidf_fast(sred[tid][0] + sred[tid][1] + sred[tid][2] + sred[tid][3] + bp[0]);
}

// ---------------------------------------------------------------------------
extern "C" void kernel_launch(void* const* d_in, const int* in_sizes, int n_in,
                              void* d_out, int out_size, void* d_ws, size_t ws_size,
                              hipStream_t stream) {
    const int*   q   = (const int*)d_in[0];
    const int*   r   = (const int*)d_in[1];
    const float* Ek  = (const float*)d_in[2];
    const float* Ev  = (const float*)d_in[3];
    const float* Mk  = (const float*)d_in[4];
    const float* Mv0 = (const float*)d_in[5];
    const float* We  = (const float*)d_in[6];
    const float* be  = (const float*)d_in[7];
    const float* Wa  = (const float*)d_in[8];
    const float* ba  = (const float*)d_in[9];
    const float* Wf  = (const float*)d_in[10];
    const float* bfv = (const float*)d_in[11];
    const float* Wp  = (const float*)d_in[12];
    const float* bp  = (const float*)d_in[13];
    float* out = (float*)d_out;

    float*  ws     = (float*)d_ws;
    float*  w_buf  = ws;                                      // 8 MB
    float2* ea_buf = (float2*)(w_buf + (size_t)NROWS * MM);   // 32 MB
    float*  rd     = (float*)(ea_buf + (size_t)NROWS * DIM);  // 16 MB

    // prepped bf16 data right after rd (~1.1 MB)
    u16* weT_hi = (u16*)(rd + (size_t)NROWS * DIM);
    u16* weT_lo = weT_hi + 16384;
    u16* waT_hi = weT_lo + 16384;
    u16* waT_lo = waT_hi + 16384;
    u16* wfT_hi = waT_lo + 16384;
    u16* wfT_lo = wfT_hi + 32768;
    u16* mkT_hi = wfT_lo + 32768;
    u16* mkT_lo = mkT_hi + 8192;
    u16* ekbf   = mkT_lo + 8192;      // 128000 u16
    u16* evbf   = ekbf + 128000;      // 256000 u16

    kP<<<dim3(128), 256, 0, stream>>>(We, Wa, Wf, Mk, Ek, Ev,
                                      weT_hi, weT_lo, waT_hi, waT_lo,
                                      wfT_hi, wfT_lo, mkT_hi, mkT_lo, ekbf, evbf);
    kAB<<<dim3(1024), 256, 0, stream>>>(q, r, ekbf, evbf, mkT_hi, mkT_lo,
                                        weT_hi, weT_lo, waT_hi, waT_lo,
                                        be, ba, w_buf, ea_buf);
    kC<<<dim3(4, BB), 256, 0, stream>>>(Mv0, w_buf, ea_buf, rd);
    kD<<<dim3(NROWS / 64), 256, 0, stream>>>(q, ekbf, wfT_hi, wfT_lo, bfv, Wp, bp, rd, out);
}

// Round 11
// 170.207 us; speedup vs baseline: 1.0453x; 1.0453x over previous
//
#include <hip/hip_runtime.h>
#include <hip/hip_bf16.h>

#define NUM_C 1000
#define DIM   128
#define MM    64
#define BB    64
#define LL    512
#define NROWS (BB * LL)   // 32768

typedef unsigned short u16;
typedef unsigned int   u32;
typedef short bfrag __attribute__((ext_vector_type(8)));   // 8 bf16 (4 VGPRs)
typedef float f32x4 __attribute__((ext_vector_type(4)));   // MFMA acc
typedef float f32x2 __attribute__((ext_vector_type(2)));   // packed f32 pair
typedef float f32x4e __attribute__((ext_vector_type(4)));

__device__ __forceinline__ float sigmoidf_fast(float x) { return 1.f / (1.f + __expf(-x)); }
__device__ __forceinline__ float tanhf_fast(float x) { return 1.f - 2.f / (__expf(2.f * x) + 1.f); }

__device__ __forceinline__ u16 f2bf(float x) {            // RNE f32->bf16 bits
    u32 u = __float_as_uint(x);
    return (u16)((u + 0x7FFFu + ((u >> 16) & 1u)) >> 16);
}
__device__ __forceinline__ float bf2f(u16 h) { return __uint_as_float(((u32)h) << 16); }

// DPP quad_perm swaps + row rotates (VALU-only, verified rounds 5-14)
__device__ __forceinline__ float quad_swap1(float x) {
    return __int_as_float(__builtin_amdgcn_mov_dpp(__float_as_int(x), 0xB1, 0xF, 0xF, true));
}
__device__ __forceinline__ float quad_swap2(float x) {
    return __int_as_float(__builtin_amdgcn_mov_dpp(__float_as_int(x), 0x4E, 0xF, 0xF, true));
}
__device__ __forceinline__ float row_ror4(float x) {
    return __int_as_float(__builtin_amdgcn_mov_dpp(__float_as_int(x), 0x124, 0xF, 0xF, true));
}
__device__ __forceinline__ float row_ror8(float x) {
    return __int_as_float(__builtin_amdgcn_mov_dpp(__float_as_int(x), 0x128, 0xF, 0xF, true));
}

// async global->LDS DMA, 16B per lane, LDS dest = wave-uniform base + lane*16
__device__ __forceinline__ void ld16(const void* g, void* l) {
    __builtin_amdgcn_global_load_lds(
        (const __attribute__((address_space(1))) unsigned int*)g,
        (__attribute__((address_space(3))) unsigned int*)l, 16, 0, 0);
}

// ---------------------------------------------------------------------------
// Prep: B-side weights as bf16 hi/lo ([n][k] transposed); A-side embeddings
// Ek/Ev pre-converted to bf16 hi ONCE (removes per-row conversion in kAB/kD).
// ---------------------------------------------------------------------------
__global__ __launch_bounds__(256) void kP(const float* __restrict__ We,
                                          const float* __restrict__ Wa,
                                          const float* __restrict__ Wf,
                                          const float* __restrict__ Mk,
                                          const float* __restrict__ Ek,
                                          const float* __restrict__ Ev,
                                          u16* weT_hi, u16* weT_lo,
                                          u16* waT_hi, u16* waT_lo,
                                          u16* wfT_hi, u16* wfT_lo,
                                          u16* mkT_hi, u16* mkT_lo,
                                          u16* ekbf, u16* evbf) {
    int idx = blockIdx.x * 256 + threadIdx.x;   // 0..32767
    if (idx < 128 * 128) {
        int n = idx >> 7, k = idx & 127;
        float we = We[k * DIM + n];
        u16 h = f2bf(we);
        weT_hi[idx] = h; weT_lo[idx] = f2bf(we - bf2f(h));
        float wa = Wa[k * DIM + n];
        u16 h2 = f2bf(wa);
        waT_hi[idx] = h2; waT_lo[idx] = f2bf(wa - bf2f(h2));
    }
    if (idx < 64 * 128) {
        float mk = Mk[idx];
        u16 h = f2bf(mk);
        mkT_hi[idx] = h; mkT_lo[idx] = f2bf(mk - bf2f(h));
    }
    {
        int n = idx >> 8, k = idx & 255;
        float wf = Wf[k * DIM + n];
        u16 h = f2bf(wf);
        wfT_hi[idx] = h; wfT_lo[idx] = f2bf(wf - bf2f(h));
    }
    for (int i = idx; i < NUM_C * DIM; i += 32768) ekbf[i] = f2bf(Ek[i]);
    for (int i = idx; i < 2 * NUM_C * DIM; i += 32768) evbf[i] = f2bf(Ev[i]);
}

// ---------------------------------------------------------------------------
// Fused kAB (MFMA, A=bf16-hi only, B=hi+lo). Blocks [0,512): kA role.
// Blocks [512,1024): kB role. 64 rows/block; staging = pure u16 gather.
// f32 outputs (r15/r20 interface).
// ---------------------------------------------------------------------------
__global__ __launch_bounds__(256) void kAB(const int* __restrict__ q,
                                           const int* __restrict__ r,
                                           const u16* __restrict__ ekbf,
                                           const u16* __restrict__ evbf,
                                           const u16* __restrict__ mkT_hi, const u16* __restrict__ mkT_lo,
                                           const u16* __restrict__ weT_hi, const u16* __restrict__ weT_lo,
                                           const u16* __restrict__ waT_hi, const u16* __restrict__ waT_lo,
                                           const float* __restrict__ be, const float* __restrict__ ba,
                                           float* __restrict__ w_out,
                                           float2* __restrict__ ea_out) {
    __shared__ __align__(16) u16 shi[4][16][136];
    __shared__ float slab[4][64];
    const int tid = threadIdx.x;
    const int lane = tid & 63;
    const int wv = tid >> 6;
    const int nloc = lane & 15;
    const int quad = lane >> 4;

    if (blockIdx.x < 512) {
        // ---------------- kA role ----------------
        const int base = blockIdx.x * 64;
        {   // stage k = ekbf[q] (already bf16)
            const int row_l = tid >> 2;
            const int rts = row_l >> 4, ms = row_l & 15;
            const int d0 = (tid & 3) * 32;
            const u16* src = ekbf + (size_t)q[base + row_l] * DIM + d0;
            #pragma unroll
            for (int c8 = 0; c8 < 4; ++c8)
                *reinterpret_cast<bfrag*>(&shi[rts][ms][d0 + c8 * 8]) =
                    *reinterpret_cast<const bfrag*>(src + c8 * 8);
        }
        __syncthreads();

        const int n = wv * 16 + nloc;      // m index
        bfrag Bh[4], Bl[4];
        #pragma unroll
        for (int kc = 0; kc < 4; ++kc) {
            const int ko = kc * 32 + quad * 8;
            Bh[kc] = *reinterpret_cast<const bfrag*>(mkT_hi + n * DIM + ko);
            Bl[kc] = *reinterpret_cast<const bfrag*>(mkT_lo + n * DIM + ko);
        }

        f32x4 acc[4];
        #pragma unroll
        for (int t = 0; t < 4; ++t) acc[t] = 0.f;

        #pragma unroll
        for (int rt = 0; rt < 4; ++rt) {
            #pragma unroll
            for (int kc = 0; kc < 4; ++kc) {
                const int ko = kc * 32 + quad * 8;
                bfrag Ah = *reinterpret_cast<const bfrag*>(&shi[rt][nloc][ko]);
                acc[rt] = __builtin_amdgcn_mfma_f32_16x16x32_bf16(Ah, Bh[kc], acc[rt], 0, 0, 0);
                acc[rt] = __builtin_amdgcn_mfma_f32_16x16x32_bf16(Ah, Bl[kc], acc[rt], 0, 0, 0);
            }
        }

        float ex[4][4];
        #pragma unroll
        for (int rt = 0; rt < 4; ++rt) {
            #pragma unroll
            for (int rg = 0; rg < 4; ++rg) {
                float e = __expf(acc[rt][rg]);
                ex[rt][rg] = e;
                float s = e;
                s += __shfl_xor(s, 1);
                s += __shfl_xor(s, 2);
                s += __shfl_xor(s, 4);
                s += __shfl_xor(s, 8);
                if (nloc == 0) slab[wv][rt * 16 + quad * 4 + rg] = s;
            }
        }
        __syncthreads();

        #pragma unroll
        for (int rt = 0; rt < 4; ++rt) {
            #pragma unroll
            for (int rg = 0; rg < 4; ++rg) {
                const int row = rt * 16 + quad * 4 + rg;
                float tot = slab[0][row] + slab[1][row] + slab[2][row] + slab[3][row];
                w_out[(size_t)(base + row) * MM + n] = ex[rt][rg] / tot;
            }
        }
    } else {
        // ---------------- kB role ----------------
        const int base = (blockIdx.x - 512) * 64;
        {   // stage v = evbf[x] (already bf16)
            const int row_l = tid >> 2;
            const int rts = row_l >> 4, ms = row_l & 15;
            const int d0 = (tid & 3) * 32;
            const int row = base + row_l;
            const int x = q[row] + NUM_C * r[row];
            const u16* src = evbf + (size_t)x * DIM + d0;
            #pragma unroll
            for (int c8 = 0; c8 < 4; ++c8)
                *reinterpret_cast<bfrag*>(&shi[rts][ms][d0 + c8 * 8]) =
                    *reinterpret_cast<const bfrag*>(src + c8 * 8);
        }
        __syncthreads();

        #pragma unroll
        for (int dt = 0; dt < 2; ++dt) {
            const int n = (wv * 2 + dt) * 16 + nloc;
            bfrag Beh[4], Bel[4], Bah[4], Bal[4];
            #pragma unroll
            for (int kc = 0; kc < 4; ++kc) {
                const int ko = kc * 32 + quad * 8;
                Beh[kc] = *reinterpret_cast<const bfrag*>(weT_hi + n * DIM + ko);
                Bel[kc] = *reinterpret_cast<const bfrag*>(weT_lo + n * DIM + ko);
                Bah[kc] = *reinterpret_cast<const bfrag*>(waT_hi + n * DIM + ko);
                Bal[kc] = *reinterpret_cast<const bfrag*>(waT_lo + n * DIM + ko);
            }
            f32x4 acc_e[4], acc_a[4];
            #pragma unroll
            for (int t = 0; t < 4; ++t) { acc_e[t] = 0.f; acc_a[t] = 0.f; }

            #pragma unroll
            for (int rt = 0; rt < 4; ++rt) {
                #pragma unroll
                for (int kc = 0; kc < 4; ++kc) {
                    const int ko = kc * 32 + quad * 8;
                    bfrag Ah = *reinterpret_cast<const bfrag*>(&shi[rt][nloc][ko]);
                    acc_e[rt] = __builtin_amdgcn_mfma_f32_16x16x32_bf16(Ah, Beh[kc], acc_e[rt], 0, 0, 0);
                    acc_a[rt] = __builtin_amdgcn_mfma_f32_16x16x32_bf16(Ah, Bah[kc], acc_a[rt], 0, 0, 0);
                    acc_e[rt] = __builtin_amdgcn_mfma_f32_16x16x32_bf16(Ah, Bel[kc], acc_e[rt], 0, 0, 0);
                    acc_a[rt] = __builtin_amdgcn_mfma_f32_16x16x32_bf16(Ah, Bal[kc], acc_a[rt], 0, 0, 0);
                }
            }
            const float bev = be[n], bav = ba[n];
            #pragma unroll
            for (int rt = 0; rt < 4; ++rt) {
                #pragma unroll
                for (int rg = 0; rg < 4; ++rg) {
                    const int row = base + rt * 16 + quad * 4 + rg;
                    float2 ea;
                    ea.x = sigmoidf_fast(acc_e[rt][rg] + bev);
                    ea.y = tanhf_fast(acc_a[rt][rg] + bav);
                    ea_out[(size_t)row * DIM + n] = ea;
                }
            }
        }
    }
}

// ---------------------------------------------------------------------------
// Kernel C (r23 = r20 base + packed-f32 math + PF=6):
//  - r20 structure kept exactly (n=4 m/thread, 16p x 16dl, 256-thr blocks,
//    grid (8,BB) = 2 blocks/CU, serial DPP reduce, f32 tiles, f32 rd).
//  - FMA work expressed as ext_vector(2) float ops (__builtin_elementwise_fma)
//    so the backend can emit v_pk_mul_f32 / v_pk_fma_f32 (VOP3P dual-f32):
//    part = 2 pk + combine (was 4+1), update = 4 pk (was 8). Same fma tree
//    per element -> bit-identical numerics. If the backend scalarizes, this
//    compiles to exactly r20's instruction stream (safe downside).
//  - Prefetch distance 4 -> 6: at 2 waves/SIMD a wave issues only ~88 own
//    cycles/step; PF=4 gave ~176 cy load->use separation vs ~120-200 cy
//    contended LDS latency. PF=6 -> ~264 cy. +12 VGPR, no occupancy change.
// ---------------------------------------------------------------------------
__device__ __forceinline__ void scan32(const float* wb, const float2* eab,
                                       int m0, int dl, int p, int t0,
                                       f32x2 (&Mv)[2], float* rp) {
    constexpr int PF = 6;
    f32x4e wq[PF];
    f32x2  eq[PF];
    #pragma unroll
    for (int u = 0; u < PF; ++u) {
        wq[u] = *reinterpret_cast<const f32x4e*>(wb + u * 64 + m0);
        eq[u] = *reinterpret_cast<const f32x2*>(&eab[u * 16 + dl]);
    }
    #pragma unroll
    for (int u = 0; u < 32; ++u) {
        f32x4e wa = wq[u % PF];
        f32x2  ea = eq[u % PF];
        if (u + PF < 32) {
            wq[u % PF] = *reinterpret_cast<const f32x4e*>(wb + (u + PF) * 64 + m0);
            eq[u % PF] = *reinterpret_cast<const f32x2*>(&eab[(u + PF) * 16 + dl]);
        }
        f32x2 w01 = __builtin_shufflevector(wa, wa, 0, 1);
        f32x2 w23 = __builtin_shufflevector(wa, wa, 2, 3);
        f32x2 ee  = __builtin_shufflevector(ea, ea, 0, 0);
        f32x2 aa  = __builtin_shufflevector(ea, ea, 1, 1);
        f32x2 o01 = Mv[0], o23 = Mv[1];

        f32x2 t = w01 * o01;                             // v_pk_mul_f32
        t = __builtin_elementwise_fma(w23, o23, t);      // v_pk_fma_f32
        float part = t[0] + t[1];

        f32x2 g01 = __builtin_elementwise_fma(-o01, ee, aa);
        f32x2 g23 = __builtin_elementwise_fma(-o23, ee, aa);
        Mv[0] = __builtin_elementwise_fma(w01, g01, o01);
        Mv[1] = __builtin_elementwise_fma(w23, g23, o23);

        part += quad_swap1(part);
        part += quad_swap2(part);
        part += row_ror4(part);
        part += row_ror8(part);       // full 16-lane (64-m) sum
        if (p == 0) rp[(size_t)(t0 + u) * DIM] = part;
    }
}

__global__ __launch_bounds__(256) void kC(const float* __restrict__ Mv0,
                                          const float* __restrict__ w_in,
                                          const float2* __restrict__ ea_in,
                                          float* __restrict__ rd) {
    __shared__ __align__(16) float  wlds[2][32][64];    // 16 KB
    __shared__ __align__(16) float2 ealds[2][32][16];   // 8 KB
    const int tid = threadIdx.x;
    const int p  = tid & 15;          // m-group 0..15
    const int dl = tid >> 4;          // d within slice 0..15
    const int ds = blockIdx.x;        // d-chunk 0..7
    const int b  = blockIdx.y;        // batch
    const int d  = ds * 16 + dl;
    const int m0 = p * 4;

    const char* wsrc  = (const char*)(w_in + (size_t)b * LL * MM);
    const char* easrc = (const char*)(ea_in + (size_t)b * LL * DIM + ds * 16);
    float* rp = rd + (size_t)b * LL * DIM + d;

    auto dma = [&](int c, int bufi) {
        const char* wt = wsrc + (size_t)c * 8192;         // w tile: 32x64 f32 = 8 KB
        char* wl = (char*)&wlds[bufi][0][0];
        const int off = tid * 16;                         // 0..4095
        ld16(wt + off, wl + off);
        ld16(wt + 4096 + off, wl + 4096 + off);
        // ea tile: 32 rows x 16 d x 8 B = 4 KB; 128 B per row, 8 lanes/row
        const int tl = tid >> 3, wi = (tid & 7) * 16;
        ld16(easrc + (size_t)(c * 32 + tl) * (DIM * 8) + wi,
             (char*)&ealds[bufi][0][0] + tid * 16);
    };

    dma(0, 0);

    f32x2 Mv[2];
    Mv[0] = (f32x2){Mv0[(m0 + 0) * DIM + d], Mv0[(m0 + 1) * DIM + d]};
    Mv[1] = (f32x2){Mv0[(m0 + 2) * DIM + d], Mv0[(m0 + 3) * DIM + d]};

    __builtin_amdgcn_s_waitcnt(0x0F70);   // vmcnt(0): tile-0 DMA + Mv loads done
    __syncthreads();

    int buf = 0;
    for (int c = 0; c < LL / 32; ++c) {
        if (c + 1 < LL / 32) dma(c + 1, buf ^ 1);
        scan32(&wlds[buf][0][0], &ealds[buf][0][0], m0, dl, p, c * 32, Mv, rp);
        if (c + 1 < LL / 32) {
            __builtin_amdgcn_s_waitcnt(0x8F70);   // vmcnt(32): DMAs retired, stores may fly
            __syncthreads();
            buf ^= 1;
        }
    }
}

// ---------------------------------------------------------------------------
// Kernel D (MFMA, A=hi only): f = tanh([rd,k]@Wf+bf); p = sigmoid(f@Wp+bp).
// 64 rows/block; rd staged via f2bf (hi), Ek gathered pre-converted.
// ---------------------------------------------------------------------------
__global__ __launch_bounds__(256) void kD(const int* __restrict__ q,
                                          const u16* __restrict__ ekbf,
                                          const u16* __restrict__ wfT_hi, const u16* __restrict__ wfT_lo,
                                          const float* __restrict__ bfv,
                                          const float* __restrict__ Wp, const float* __restrict__ bp,
                                          const float* __restrict__ rd,
                                          float* __restrict__ out) {
    __shared__ __align__(16) u16 xhi[4][16][264];   // 33792 B (fbuf overlays exactly)
    __shared__ float sred[64][4];
    const int tid = threadIdx.x;
    const int base = blockIdx.x * 64;
    const int row_l = tid >> 2;
    const int rts = row_l >> 4, ms = row_l & 15;
    const int d0 = (tid & 3) * 32;
    const int row = base + row_l;

    {   // x[:, 0:128) = rd -> bf16 hi
        const float* src = rd + (size_t)row * DIM + d0;
        #pragma unroll
        for (int c8 = 0; c8 < 4; ++c8) {
            float4 f0 = *reinterpret_cast<const float4*>(src + c8 * 8);
            float4 f1 = *reinterpret_cast<const float4*>(src + c8 * 8 + 4);
            float xs[8] = {f0.x, f0.y, f0.z, f0.w, f1.x, f1.y, f1.z, f1.w};
            bfrag h;
            #pragma unroll
            for (int j = 0; j < 8; ++j) h[j] = (short)f2bf(xs[j]);
            *reinterpret_cast<bfrag*>(&xhi[rts][ms][d0 + c8 * 8]) = h;
        }
    }
    {   // x[:, 128:256) = ekbf[q[row]] (already bf16)
        const u16* src = ekbf + (size_t)q[row] * DIM + d0;
        #pragma unroll
        for (int c8 = 0; c8 < 4; ++c8)
            *reinterpret_cast<bfrag*>(&xhi[rts][ms][128 + d0 + c8 * 8]) =
                *reinterpret_cast<const bfrag*>(src + c8 * 8);
    }
    __syncthreads();

    const int lane = tid & 63;
    const int wv = tid >> 6;
    const int nloc = lane & 15;
    const int quad = lane >> 4;
    float* fbuf = reinterpret_cast<float*>(&xhi[0][0][0]);   // overlay after sync

    f32x4 acc[2][4];
    #pragma unroll
    for (int dt = 0; dt < 2; ++dt)
        #pragma unroll
        for (int t = 0; t < 4; ++t) acc[dt][t] = 0.f;

    #pragma unroll
    for (int dt = 0; dt < 2; ++dt) {
        const int n = (wv * 2 + dt) * 16 + nloc;
        bfrag Bh[8], Bl[8];
        #pragma unroll
        for (int kc = 0; kc < 8; ++kc) {
            const int ko = kc * 32 + quad * 8;
            Bh[kc] = *reinterpret_cast<const bfrag*>(wfT_hi + n * 256 + ko);
            Bl[kc] = *reinterpret_cast<const bfrag*>(wfT_lo + n * 256 + ko);
        }
        #pragma unroll
        for (int rt = 0; rt < 4; ++rt) {
            #pragma unroll
            for (int kc = 0; kc < 8; ++kc) {
                const int ko = kc * 32 + quad * 8;
                bfrag Ah = *reinterpret_cast<const bfrag*>(&xhi[rt][nloc][ko]);
                acc[dt][rt] = __builtin_amdgcn_mfma_f32_16x16x32_bf16(Ah, Bh[kc], acc[dt][rt], 0, 0, 0);
                acc[dt][rt] = __builtin_amdgcn_mfma_f32_16x16x32_bf16(Ah, Bl[kc], acc[dt][rt], 0, 0, 0);
            }
        }
    }
    __syncthreads();   // LDS x reads done before fbuf overlay

    #pragma unroll
    for (int dt = 0; dt < 2; ++dt) {
        const int n = (wv * 2 + dt) * 16 + nloc;
        const float bfn = bfv[n], wpn = Wp[n];
        #pragma unroll
        for (int rt = 0; rt < 4; ++rt)
            #pragma unroll
            for (int rg = 0; rg < 4; ++rg)
                fbuf[(rt * 16 + quad * 4 + rg) * 132 + n] = tanhf_fast(acc[dt][rt][rg] + bfn) * wpn;
    }
    __syncthreads();

    {
        float s = 0.f;
        const int c = tid & 3;
        #pragma unroll
        for (int k = 0; k < 32; ++k) s += fbuf[row_l * 132 + c * 32 + k];
        sred[row_l][c] = s;
    }
    __syncthreads();
    if (tid < 64)
        out[base + tid] = sigmoidf_fast(sred[tid][0] + sred[tid][1] + sred[tid][2] + sred[tid][3] + bp[0]);
}

// ---------------------------------------------------------------------------
extern "C" void kernel_launch(void* const* d_in, const int* in_sizes, int n_in,
                              void* d_out, int out_size, void* d_ws, size_t ws_size,
                              hipStream_t stream) {
    const int*   q   = (const int*)d_in[0];
    const int*   r   = (const int*)d_in[1];
    const float* Ek  = (const float*)d_in[2];
    const float* Ev  = (const float*)d_in[3];
    const float* Mk  = (const float*)d_in[4];
    const float* Mv0 = (const float*)d_in[5];
    const float* We  = (const float*)d_in[6];
    const float* be  = (const float*)d_in[7];
    const float* Wa  = (const float*)d_in[8];
    const float* ba  = (const float*)d_in[9];
    const float* Wf  = (const float*)d_in[10];
    const float* bfv = (const float*)d_in[11];
    const float* Wp  = (const float*)d_in[12];
    const float* bp  = (const float*)d_in[13];
    float* out = (float*)d_out;

    float*  ws     = (float*)d_ws;
    float*  w_buf  = ws;                                      // 8 MB
    float2* ea_buf = (float2*)(w_buf + (size_t)NROWS * MM);   // 32 MB
    float*  rd     = (float*)(ea_buf + (size_t)NROWS * DIM);  // 16 MB

    // prepped bf16 data right after rd (~1.1 MB)
    u16* weT_hi = (u16*)(rd + (size_t)NROWS * DIM);
    u16* weT_lo = weT_hi + 16384;
    u16* waT_hi = weT_lo + 16384;
    u16* waT_lo = waT_hi + 16384;
    u16* wfT_hi = waT_lo + 16384;
    u16* wfT_lo = wfT_hi + 32768;
    u16* mkT_hi = wfT_lo + 32768;
    u16* mkT_lo = mkT_hi + 8192;
    u16* ekbf   = mkT_lo + 8192;      // 128000 u16
    u16* evbf   = ekbf + 128000;      // 256000 u16

    kP<<<dim3(128), 256, 0, stream>>>(We, Wa, Wf, Mk, Ek, Ev,
                                      weT_hi, weT_lo, waT_hi, waT_lo,
                                      wfT_hi, wfT_lo, mkT_hi, mkT_lo, ekbf, evbf);
    kAB<<<dim3(1024), 256, 0, stream>>>(q, r, ekbf, evbf, mkT_hi, mkT_lo,
                                        weT_hi, weT_lo, waT_hi, waT_lo,
                                        be, ba, w_buf, ea_buf);
    kC<<<dim3(8, BB), 256, 0, stream>>>(Mv0, w_buf, ea_buf, rd);
    kD<<<dim3(NROWS / 64), 256, 0, stream>>>(q, ekbf, wfT_hi, wfT_lo, bfv, Wp, bp, rd, out);
}

// Round 12
// 169.016 us; speedup vs baseline: 1.0527x; 1.0071x over previous
//
#include <hip/hip_runtime.h>
#include <hip/hip_bf16.h>

#define NUM_C 1000
#define DIM   128
#define MM    64
#define BB    64
#define LL    512
#define NROWS (BB * LL)   // 32768

typedef unsigned short u16;
typedef unsigned int   u32;
typedef short bfrag __attribute__((ext_vector_type(8)));   // 8 bf16 (4 VGPRs)
typedef float f32x4 __attribute__((ext_vector_type(4)));   // MFMA acc

__device__ __forceinline__ float sigmoidf_fast(float x) { return 1.f / (1.f + __expf(-x)); }
__device__ __forceinline__ float tanhf_fast(float x) { return 1.f - 2.f / (__expf(2.f * x) + 1.f); }

__device__ __forceinline__ u16 f2bf(float x) {            // RNE f32->bf16 bits
    u32 u = __float_as_uint(x);
    return (u16)((u + 0x7FFFu + ((u >> 16) & 1u)) >> 16);
}
__device__ __forceinline__ float bf2f(u16 h) { return __uint_as_float(((u32)h) << 16); }

// DPP quad_perm swaps + row rotates (VALU-only, verified rounds 5-14)
__device__ __forceinline__ float quad_swap1(float x) {
    return __int_as_float(__builtin_amdgcn_mov_dpp(__float_as_int(x), 0xB1, 0xF, 0xF, true));
}
__device__ __forceinline__ float quad_swap2(float x) {
    return __int_as_float(__builtin_amdgcn_mov_dpp(__float_as_int(x), 0x4E, 0xF, 0xF, true));
}
__device__ __forceinline__ float row_ror4(float x) {
    return __int_as_float(__builtin_amdgcn_mov_dpp(__float_as_int(x), 0x124, 0xF, 0xF, true));
}
__device__ __forceinline__ float row_ror8(float x) {
    return __int_as_float(__builtin_amdgcn_mov_dpp(__float_as_int(x), 0x128, 0xF, 0xF, true));
}

// async global->LDS DMA, 16B per lane, LDS dest = wave-uniform base + lane*16
__device__ __forceinline__ void ld16(const void* g, void* l) {
    __builtin_amdgcn_global_load_lds(
        (const __attribute__((address_space(1))) unsigned int*)g,
        (__attribute__((address_space(3))) unsigned int*)l, 16, 0, 0);
}

// ---------------------------------------------------------------------------
// Prep: B-side weights as bf16 hi/lo ([n][k] transposed); A-side embeddings
// Ek/Ev pre-converted to bf16 hi ONCE (removes per-row conversion in kAB/kD).
// ---------------------------------------------------------------------------
__global__ __launch_bounds__(256) void kP(const float* __restrict__ We,
                                          const float* __restrict__ Wa,
                                          const float* __restrict__ Wf,
                                          const float* __restrict__ Mk,
                                          const float* __restrict__ Ek,
                                          const float* __restrict__ Ev,
                                          u16* weT_hi, u16* weT_lo,
                                          u16* waT_hi, u16* waT_lo,
                                          u16* wfT_hi, u16* wfT_lo,
                                          u16* mkT_hi, u16* mkT_lo,
                                          u16* ekbf, u16* evbf) {
    int idx = blockIdx.x * 256 + threadIdx.x;   // 0..32767
    if (idx < 128 * 128) {
        int n = idx >> 7, k = idx & 127;
        float we = We[k * DIM + n];
        u16 h = f2bf(we);
        weT_hi[idx] = h; weT_lo[idx] = f2bf(we - bf2f(h));
        float wa = Wa[k * DIM + n];
        u16 h2 = f2bf(wa);
        waT_hi[idx] = h2; waT_lo[idx] = f2bf(wa - bf2f(h2));
    }
    if (idx < 64 * 128) {
        float mk = Mk[idx];
        u16 h = f2bf(mk);
        mkT_hi[idx] = h; mkT_lo[idx] = f2bf(mk - bf2f(h));
    }
    {
        int n = idx >> 8, k = idx & 255;
        float wf = Wf[k * DIM + n];
        u16 h = f2bf(wf);
        wfT_hi[idx] = h; wfT_lo[idx] = f2bf(wf - bf2f(h));
    }
    for (int i = idx; i < NUM_C * DIM; i += 32768) ekbf[i] = f2bf(Ek[i]);
    for (int i = idx; i < 2 * NUM_C * DIM; i += 32768) evbf[i] = f2bf(Ev[i]);
}

// ---------------------------------------------------------------------------
// Fused kAB (MFMA, A=bf16-hi only, B=hi+lo). Blocks [0,512): kA role.
// Blocks [512,1024): kB role. 64 rows/block; staging = pure u16 gather.
// f32 outputs (r15/r20 interface).
// ---------------------------------------------------------------------------
__global__ __launch_bounds__(256) void kAB(const int* __restrict__ q,
                                           const int* __restrict__ r,
                                           const u16* __restrict__ ekbf,
                                           const u16* __restrict__ evbf,
                                           const u16* __restrict__ mkT_hi, const u16* __restrict__ mkT_lo,
                                           const u16* __restrict__ weT_hi, const u16* __restrict__ weT_lo,
                                           const u16* __restrict__ waT_hi, const u16* __restrict__ waT_lo,
                                           const float* __restrict__ be, const float* __restrict__ ba,
                                           float* __restrict__ w_out,
                                           float2* __restrict__ ea_out) {
    __shared__ __align__(16) u16 shi[4][16][136];
    __shared__ float slab[4][64];
    const int tid = threadIdx.x;
    const int lane = tid & 63;
    const int wv = tid >> 6;
    const int nloc = lane & 15;
    const int quad = lane >> 4;

    if (blockIdx.x < 512) {
        // ---------------- kA role ----------------
        const int base = blockIdx.x * 64;
        {   // stage k = ekbf[q] (already bf16)
            const int row_l = tid >> 2;
            const int rts = row_l >> 4, ms = row_l & 15;
            const int d0 = (tid & 3) * 32;
            const u16* src = ekbf + (size_t)q[base + row_l] * DIM + d0;
            #pragma unroll
            for (int c8 = 0; c8 < 4; ++c8)
                *reinterpret_cast<bfrag*>(&shi[rts][ms][d0 + c8 * 8]) =
                    *reinterpret_cast<const bfrag*>(src + c8 * 8);
        }
        __syncthreads();

        const int n = wv * 16 + nloc;      // m index
        bfrag Bh[4], Bl[4];
        #pragma unroll
        for (int kc = 0; kc < 4; ++kc) {
            const int ko = kc * 32 + quad * 8;
            Bh[kc] = *reinterpret_cast<const bfrag*>(mkT_hi + n * DIM + ko);
            Bl[kc] = *reinterpret_cast<const bfrag*>(mkT_lo + n * DIM + ko);
        }

        f32x4 acc[4];
        #pragma unroll
        for (int t = 0; t < 4; ++t) acc[t] = 0.f;

        #pragma unroll
        for (int rt = 0; rt < 4; ++rt) {
            #pragma unroll
            for (int kc = 0; kc < 4; ++kc) {
                const int ko = kc * 32 + quad * 8;
                bfrag Ah = *reinterpret_cast<const bfrag*>(&shi[rt][nloc][ko]);
                acc[rt] = __builtin_amdgcn_mfma_f32_16x16x32_bf16(Ah, Bh[kc], acc[rt], 0, 0, 0);
                acc[rt] = __builtin_amdgcn_mfma_f32_16x16x32_bf16(Ah, Bl[kc], acc[rt], 0, 0, 0);
            }
        }

        float ex[4][4];
        #pragma unroll
        for (int rt = 0; rt < 4; ++rt) {
            #pragma unroll
            for (int rg = 0; rg < 4; ++rg) {
                float e = __expf(acc[rt][rg]);
                ex[rt][rg] = e;
                float s = e;
                s += __shfl_xor(s, 1);
                s += __shfl_xor(s, 2);
                s += __shfl_xor(s, 4);
                s += __shfl_xor(s, 8);
                if (nloc == 0) slab[wv][rt * 16 + quad * 4 + rg] = s;
            }
        }
        __syncthreads();

        #pragma unroll
        for (int rt = 0; rt < 4; ++rt) {
            #pragma unroll
            for (int rg = 0; rg < 4; ++rg) {
                const int row = rt * 16 + quad * 4 + rg;
                float tot = slab[0][row] + slab[1][row] + slab[2][row] + slab[3][row];
                w_out[(size_t)(base + row) * MM + n] = ex[rt][rg] / tot;
            }
        }
    } else {
        // ---------------- kB role ----------------
        const int base = (blockIdx.x - 512) * 64;
        {   // stage v = evbf[x] (already bf16)
            const int row_l = tid >> 2;
            const int rts = row_l >> 4, ms = row_l & 15;
            const int d0 = (tid & 3) * 32;
            const int row = base + row_l;
            const int x = q[row] + NUM_C * r[row];
            const u16* src = evbf + (size_t)x * DIM + d0;
            #pragma unroll
            for (int c8 = 0; c8 < 4; ++c8)
                *reinterpret_cast<bfrag*>(&shi[rts][ms][d0 + c8 * 8]) =
                    *reinterpret_cast<const bfrag*>(src + c8 * 8);
        }
        __syncthreads();

        #pragma unroll
        for (int dt = 0; dt < 2; ++dt) {
            const int n = (wv * 2 + dt) * 16 + nloc;
            bfrag Beh[4], Bel[4], Bah[4], Bal[4];
            #pragma unroll
            for (int kc = 0; kc < 4; ++kc) {
                const int ko = kc * 32 + quad * 8;
                Beh[kc] = *reinterpret_cast<const bfrag*>(weT_hi + n * DIM + ko);
                Bel[kc] = *reinterpret_cast<const bfrag*>(weT_lo + n * DIM + ko);
                Bah[kc] = *reinterpret_cast<const bfrag*>(waT_hi + n * DIM + ko);
                Bal[kc] = *reinterpret_cast<const bfrag*>(waT_lo + n * DIM + ko);
            }
            f32x4 acc_e[4], acc_a[4];
            #pragma unroll
            for (int t = 0; t < 4; ++t) { acc_e[t] = 0.f; acc_a[t] = 0.f; }

            #pragma unroll
            for (int rt = 0; rt < 4; ++rt) {
                #pragma unroll
                for (int kc = 0; kc < 4; ++kc) {
                    const int ko = kc * 32 + quad * 8;
                    bfrag Ah = *reinterpret_cast<const bfrag*>(&shi[rt][nloc][ko]);
                    acc_e[rt] = __builtin_amdgcn_mfma_f32_16x16x32_bf16(Ah, Beh[kc], acc_e[rt], 0, 0, 0);
                    acc_a[rt] = __builtin_amdgcn_mfma_f32_16x16x32_bf16(Ah, Bah[kc], acc_a[rt], 0, 0, 0);
                    acc_e[rt] = __builtin_amdgcn_mfma_f32_16x16x32_bf16(Ah, Bel[kc], acc_e[rt], 0, 0, 0);
                    acc_a[rt] = __builtin_amdgcn_mfma_f32_16x16x32_bf16(Ah, Bal[kc], acc_a[rt], 0, 0, 0);
                }
            }
            const float bev = be[n], bav = ba[n];
            #pragma unroll
            for (int rt = 0; rt < 4; ++rt) {
                #pragma unroll
                for (int rg = 0; rg < 4; ++rg) {
                    const int row = base + rt * 16 + quad * 4 + rg;
                    float2 ea;
                    ea.x = sigmoidf_fast(acc_e[rt][rg] + bev);
                    ea.y = tanhf_fast(acc_a[rt][rg] + bav);
                    ea_out[(size_t)row * DIM + n] = ea;
                }
            }
        }
    }
}

// ---------------------------------------------------------------------------
// Kernel C (r24 = r20 base + ASM-PINNED LDS PIPELINE):
// Diagnosis: VGPR=40 across r15-r23 proves the compiler collapses every
// source-level prefetch queue (PF=6 alone needs 36 VGPRs) by sinking each
// ds_read to just before use -> full contended LDS latency (~120-200 cy)
// exposed per step = the conserved ~270 cy/step. Fix: the loads are inline
// asm (outputs forced live, instructions not reorderable among themselves),
// with counted waits (T4 applied to lgkmcnt): 2 loads/step x 4-step depth
// -> per-step s_waitcnt lgkmcnt(6), drain tail 6/4/2/0; sched_barrier(0)
// after each wait (rule #18: consumers hoist above asm waits otherwise).
// dma() uses vmcnt -> no counter interference. Addresses: AS(3) 32-bit
// bases + compile-time byte offsets. Everything else = r20/r23.
// ---------------------------------------------------------------------------
__device__ __forceinline__ void scan32(u32 wbase, u32 ebase,
                                       int t0, int p,
                                       float (&Mv)[4], float* rp) {
    float4 wq[4];
    float2 eq[4];

#define KC_LOAD(SLOT, UU)                                                     \
    asm volatile("ds_read_b128 %0, %1"                                        \
                 : "=v"(wq[SLOT]) : "v"(wbase + (UU) * 256));                 \
    asm volatile("ds_read_b64 %0, %1"                                         \
                 : "=v"(eq[SLOT]) : "v"(ebase + (UU) * 128));

    KC_LOAD(0, 0) KC_LOAD(1, 1) KC_LOAD(2, 2) KC_LOAD(3, 3)

#define KC_STEP(UU, WN) {                                                     \
    asm volatile("s_waitcnt lgkmcnt(" #WN ")");                               \
    __builtin_amdgcn_sched_barrier(0);                                        \
    float4 w4 = wq[(UU) & 3];                                                 \
    float2 ea = eq[(UU) & 3];                                                 \
    if ((UU) + 4 < 32) { KC_LOAD((UU) & 3, (UU) + 4) }                        \
    float e_c = ea.x, a_c = ea.y;                                             \
    float o0 = Mv[0], o1 = Mv[1], o2 = Mv[2], o3 = Mv[3];                     \
    float pp0 = w4.x * o0;                                                    \
    pp0 = fmaf(w4.y, o1, pp0);                                                \
    float pp1 = w4.z * o2;                                                    \
    pp1 = fmaf(w4.w, o3, pp1);                                                \
    Mv[0] = fmaf(w4.x, fmaf(-o0, e_c, a_c), o0);                              \
    Mv[1] = fmaf(w4.y, fmaf(-o1, e_c, a_c), o1);                              \
    Mv[2] = fmaf(w4.z, fmaf(-o2, e_c, a_c), o2);                              \
    Mv[3] = fmaf(w4.w, fmaf(-o3, e_c, a_c), o3);                              \
    float part = pp0 + pp1;                                                   \
    part += quad_swap1(part);                                                 \
    part += quad_swap2(part);                                                 \
    part += row_ror4(part);                                                   \
    part += row_ror8(part);                                                   \
    if (p == 0) rp[(size_t)(t0 + (UU)) * DIM] = part; }

    KC_STEP(0, 6)  KC_STEP(1, 6)  KC_STEP(2, 6)  KC_STEP(3, 6)
    KC_STEP(4, 6)  KC_STEP(5, 6)  KC_STEP(6, 6)  KC_STEP(7, 6)
    KC_STEP(8, 6)  KC_STEP(9, 6)  KC_STEP(10, 6) KC_STEP(11, 6)
    KC_STEP(12, 6) KC_STEP(13, 6) KC_STEP(14, 6) KC_STEP(15, 6)
    KC_STEP(16, 6) KC_STEP(17, 6) KC_STEP(18, 6) KC_STEP(19, 6)
    KC_STEP(20, 6) KC_STEP(21, 6) KC_STEP(22, 6) KC_STEP(23, 6)
    KC_STEP(24, 6) KC_STEP(25, 6) KC_STEP(26, 6) KC_STEP(27, 6)
    KC_STEP(28, 6) KC_STEP(29, 4) KC_STEP(30, 2) KC_STEP(31, 0)

#undef KC_STEP
#undef KC_LOAD
}

__global__ __launch_bounds__(256) void kC(const float* __restrict__ Mv0,
                                          const float* __restrict__ w_in,
                                          const float2* __restrict__ ea_in,
                                          float* __restrict__ rd) {
    __shared__ __align__(16) float  wlds[2][32][64];    // 16 KB
    __shared__ __align__(16) float2 ealds[2][32][16];   // 8 KB
    const int tid = threadIdx.x;
    const int p  = tid & 15;          // m-group 0..15
    const int dl = tid >> 4;          // d within slice 0..15
    const int ds = blockIdx.x;        // d-chunk 0..7
    const int b  = blockIdx.y;        // batch
    const int d  = ds * 16 + dl;
    const int m0 = p * 4;

    const char* wsrc  = (const char*)(w_in + (size_t)b * LL * MM);
    const char* easrc = (const char*)(ea_in + (size_t)b * LL * DIM + ds * 16);
    float* rp = rd + (size_t)b * LL * DIM + d;

    auto dma = [&](int c, int bufi) {
        const char* wt = wsrc + (size_t)c * 8192;         // w tile: 32x64 f32 = 8 KB
        char* wl = (char*)&wlds[bufi][0][0];
        const int off = tid * 16;                         // 0..4095
        ld16(wt + off, wl + off);
        ld16(wt + 4096 + off, wl + 4096 + off);
        // ea tile: 32 rows x 16 d x 8 B = 4 KB; 128 B per row, 8 lanes/row
        const int tl = tid >> 3, wi = (tid & 7) * 16;
        ld16(easrc + (size_t)(c * 32 + tl) * (DIM * 8) + wi,
             (char*)&ealds[bufi][0][0] + tid * 16);
    };

    dma(0, 0);

    float Mv[4];
    #pragma unroll
    for (int j = 0; j < 4; ++j)
        Mv[j] = Mv0[(m0 + j) * DIM + d];

    __builtin_amdgcn_s_waitcnt(0x0F70);   // vmcnt(0): tile-0 DMA + Mv loads done
    __syncthreads();

    int buf = 0;
    for (int c = 0; c < LL / 32; ++c) {
        if (c + 1 < LL / 32) dma(c + 1, buf ^ 1);
        {
            u32 wbase = (u32)(size_t)(__attribute__((address_space(3))) float*)&wlds[buf][0][0]
                        + (u32)m0 * 4u;
            u32 ebase = (u32)(size_t)(__attribute__((address_space(3))) float2*)&ealds[buf][0][0]
                        + (u32)dl * 8u;
            scan32(wbase, ebase, c * 32, p, Mv, rp);
        }
        if (c + 1 < LL / 32) {
            __builtin_amdgcn_s_waitcnt(0x8F70);   // vmcnt(32): DMAs retired, stores may fly
            __syncthreads();
            buf ^= 1;
        }
    }
}

// ---------------------------------------------------------------------------
// Kernel D (MFMA, A=hi only): f = tanh([rd,k]@Wf+bf); p = sigmoid(f@Wp+bp).
// 64 rows/block; rd staged via f2bf (hi), Ek gathered pre-converted.
// ---------------------------------------------------------------------------
__global__ __launch_bounds__(256) void kD(const int* __restrict__ q,
                                          const u16* __restrict__ ekbf,
                                          const u16* __restrict__ wfT_hi, const u16* __restrict__ wfT_lo,
                                          const float* __restrict__ bfv,
                                          const float* __restrict__ Wp, const float* __restrict__ bp,
                                          const float* __restrict__ rd,
                                          float* __restrict__ out) {
    __shared__ __align__(16) u16 xhi[4][16][264];   // 33792 B (fbuf overlays exactly)
    __shared__ float sred[64][4];
    const int tid = threadIdx.x;
    const int base = blockIdx.x * 64;
    const int row_l = tid >> 2;
    const int rts = row_l >> 4, ms = row_l & 15;
    const int d0 = (tid & 3) * 32;
    const int row = base + row_l;

    {   // x[:, 0:128) = rd -> bf16 hi
        const float* src = rd + (size_t)row * DIM + d0;
        #pragma unroll
        for (int c8 = 0; c8 < 4; ++c8) {
            float4 f0 = *reinterpret_cast<const float4*>(src + c8 * 8);
            float4 f1 = *reinterpret_cast<const float4*>(src + c8 * 8 + 4);
            float xs[8] = {f0.x, f0.y, f0.z, f0.w, f1.x, f1.y, f1.z, f1.w};
            bfrag h;
            #pragma unroll
            for (int j = 0; j < 8; ++j) h[j] = (short)f2bf(xs[j]);
            *reinterpret_cast<bfrag*>(&xhi[rts][ms][d0 + c8 * 8]) = h;
        }
    }
    {   // x[:, 128:256) = ekbf[q[row]] (already bf16)
        const u16* src = ekbf + (size_t)q[row] * DIM + d0;
        #pragma unroll
        for (int c8 = 0; c8 < 4; ++c8)
            *reinterpret_cast<bfrag*>(&xhi[rts][ms][128 + d0 + c8 * 8]) =
                *reinterpret_cast<const bfrag*>(src + c8 * 8);
    }
    __syncthreads();

    const int lane = tid & 63;
    const int wv = tid >> 6;
    const int nloc = lane & 15;
    const int quad = lane >> 4;
    float* fbuf = reinterpret_cast<float*>(&xhi[0][0][0]);   // overlay after sync

    f32x4 acc[2][4];
    #pragma unroll
    for (int dt = 0; dt < 2; ++dt)
        #pragma unroll
        for (int t = 0; t < 4; ++t) acc[dt][t] = 0.f;

    #pragma unroll
    for (int dt = 0; dt < 2; ++dt) {
        const int n = (wv * 2 + dt) * 16 + nloc;
        bfrag Bh[8], Bl[8];
        #pragma unroll
        for (int kc = 0; kc < 8; ++kc) {
            const int ko = kc * 32 + quad * 8;
            Bh[kc] = *reinterpret_cast<const bfrag*>(wfT_hi + n * 256 + ko);
            Bl[kc] = *reinterpret_cast<const bfrag*>(wfT_lo + n * 256 + ko);
        }
        #pragma unroll
        for (int rt = 0; rt < 4; ++rt) {
            #pragma unroll
            for (int kc = 0; kc < 8; ++kc) {
                const int ko = kc * 32 + quad * 8;
                bfrag Ah = *reinterpret_cast<const bfrag*>(&xhi[rt][nloc][ko]);
                acc[dt][rt] = __builtin_amdgcn_mfma_f32_16x16x32_bf16(Ah, Bh[kc], acc[dt][rt], 0, 0, 0);
                acc[dt][rt] = __builtin_amdgcn_mfma_f32_16x16x32_bf16(Ah, Bl[kc], acc[dt][rt], 0, 0, 0);
            }
        }
    }
    __syncthreads();   // LDS x reads done before fbuf overlay

    #pragma unroll
    for (int dt = 0; dt < 2; ++dt) {
        const int n = (wv * 2 + dt) * 16 + nloc;
        const float bfn = bfv[n], wpn = Wp[n];
        #pragma unroll
        for (int rt = 0; rt < 4; ++rt)
            #pragma unroll
            for (int rg = 0; rg < 4; ++rg)
                fbuf[(rt * 16 + quad * 4 + rg) * 132 + n] = tanhf_fast(acc[dt][rt][rg] + bfn) * wpn;
    }
    __syncthreads();

    {
        float s = 0.f;
        const int c = tid & 3;
        #pragma unroll
        for (int k = 0; k < 32; ++k) s += fbuf[row_l * 132 + c * 32 + k];
        sred[row_l][c] = s;
    }
    __syncthreads();
    if (tid < 64)
        out[base + tid] = sigmoidf_fast(sred[tid][0] + sred[tid][1] + sred[tid][2] + sred[tid][3] + bp[0]);
}

// ---------------------------------------------------------------------------
extern "C" void kernel_launch(void* const* d_in, const int* in_sizes, int n_in,
                              void* d_out, int out_size, void* d_ws, size_t ws_size,
                              hipStream_t stream) {
    const int*   q   = (const int*)d_in[0];
    const int*   r   = (const int*)d_in[1];
    const float* Ek  = (const float*)d_in[2];
    const float* Ev  = (const float*)d_in[3];
    const float* Mk  = (const float*)d_in[4];
    const float* Mv0 = (const float*)d_in[5];
    const float* We  = (const float*)d_in[6];
    const float* be  = (const float*)d_in[7];
    const float* Wa  = (const float*)d_in[8];
    const float* ba  = (const float*)d_in[9];
    const float* Wf  = (const float*)d_in[10];
    const float* bfv = (const float*)d_in[11];
    const float* Wp  = (const float*)d_in[12];
    const float* bp  = (const float*)d_in[13];
    float* out = (float*)d_out;

    float*  ws     = (float*)d_ws;
    float*  w_buf  = ws;                                      // 8 MB
    float2* ea_buf = (float2*)(w_buf + (size_t)NROWS * MM);   // 32 MB
    float*  rd     = (float*)(ea_buf + (size_t)NROWS * DIM);  // 16 MB

    // prepped bf16 data right after rd (~1.1 MB)
    u16* weT_hi = (u16*)(rd + (size_t)NROWS * DIM);
    u16* weT_lo = weT_hi + 16384;
    u16* waT_hi = weT_lo + 16384;
    u16* waT_lo = waT_hi + 16384;
    u16* wfT_hi = waT_lo + 16384;
    u16* wfT_lo = wfT_hi + 32768;
    u16* mkT_hi = wfT_lo + 32768;
    u16* mkT_lo = mkT_hi + 8192;
    u16* ekbf   = mkT_lo + 8192;      // 128000 u16
    u16* evbf   = ekbf + 128000;      // 256000 u16

    kP<<<dim3(128), 256, 0, stream>>>(We, Wa, Wf, Mk, Ek, Ev,
                                      weT_hi, weT_lo, waT_hi, waT_lo,
                                      wfT_hi, wfT_lo, mkT_hi, mkT_lo, ekbf, evbf);
    kAB<<<dim3(1024), 256, 0, stream>>>(q, r, ekbf, evbf, mkT_hi, mkT_lo,
                                        weT_hi, weT_lo, waT_hi, waT_lo,
                                        be, ba, w_buf, ea_buf);
    kC<<<dim3(8, BB), 256, 0, stream>>>(Mv0, w_buf, ea_buf, rd);
    kD<<<dim3(NROWS / 64), 256, 0, stream>>>(q, ekbf, wfT_hi, wfT_lo, bfv, Wp, bp, rd, out);
}

// Round 14
// 167.130 us; speedup vs baseline: 1.0646x; 1.0113x over previous
//
#include <hip/hip_runtime.h>
#include <hip/hip_bf16.h>

#define NUM_C 1000
#define DIM   128
#define MM    64
#define BB    64
#define LL    512
#define NROWS (BB * LL)   // 32768

typedef unsigned short u16;
typedef unsigned int   u32;
typedef short bfrag __attribute__((ext_vector_type(8)));   // 8 bf16 (4 VGPRs)
typedef float f32x4 __attribute__((ext_vector_type(4)));   // MFMA acc

__device__ __forceinline__ float sigmoidf_fast(float x) { return 1.f / (1.f + __expf(-x)); }
__device__ __forceinline__ float tanhf_fast(float x) { return 1.f - 2.f / (__expf(2.f * x) + 1.f); }

__device__ __forceinline__ u16 f2bf(float x) {            // RNE f32->bf16 bits
    u32 u = __float_as_uint(x);
    return (u16)((u + 0x7FFFu + ((u >> 16) & 1u)) >> 16);
}
__device__ __forceinline__ float bf2f(u16 h) { return __uint_as_float(((u32)h) << 16); }

// DPP quad_perm swaps + row rotates (VALU-only, verified rounds 5-14)
__device__ __forceinline__ float quad_swap1(float x) {
    return __int_as_float(__builtin_amdgcn_mov_dpp(__float_as_int(x), 0xB1, 0xF, 0xF, true));
}
__device__ __forceinline__ float quad_swap2(float x) {
    return __int_as_float(__builtin_amdgcn_mov_dpp(__float_as_int(x), 0x4E, 0xF, 0xF, true));
}
__device__ __forceinline__ float row_ror4(float x) {
    return __int_as_float(__builtin_amdgcn_mov_dpp(__float_as_int(x), 0x124, 0xF, 0xF, true));
}
__device__ __forceinline__ float row_ror8(float x) {
    return __int_as_float(__builtin_amdgcn_mov_dpp(__float_as_int(x), 0x128, 0xF, 0xF, true));
}

// async global->LDS DMA, 16B per lane, LDS dest = wave-uniform base + lane*16
__device__ __forceinline__ void ld16(const void* g, void* l) {
    __builtin_amdgcn_global_load_lds(
        (const __attribute__((address_space(1))) unsigned int*)g,
        (__attribute__((address_space(3))) unsigned int*)l, 16, 0, 0);
}

// ---------------------------------------------------------------------------
// Prep: B-side weights as bf16 hi/lo ([n][k] transposed); A-side embeddings
// Ek/Ev pre-converted to bf16 hi ONCE (removes per-row conversion in kAB/kD).
// ---------------------------------------------------------------------------
__global__ __launch_bounds__(256) void kP(const float* __restrict__ We,
                                          const float* __restrict__ Wa,
                                          const float* __restrict__ Wf,
                                          const float* __restrict__ Mk,
                                          const float* __restrict__ Ek,
                                          const float* __restrict__ Ev,
                                          u16* weT_hi, u16* weT_lo,
                                          u16* waT_hi, u16* waT_lo,
                                          u16* wfT_hi, u16* wfT_lo,
                                          u16* mkT_hi, u16* mkT_lo,
                                          u16* ekbf, u16* evbf) {
    int idx = blockIdx.x * 256 + threadIdx.x;   // 0..32767
    if (idx < 128 * 128) {
        int n = idx >> 7, k = idx & 127;
        float we = We[k * DIM + n];
        u16 h = f2bf(we);
        weT_hi[idx] = h; weT_lo[idx] = f2bf(we - bf2f(h));
        float wa = Wa[k * DIM + n];
        u16 h2 = f2bf(wa);
        waT_hi[idx] = h2; waT_lo[idx] = f2bf(wa - bf2f(h2));
    }
    if (idx < 64 * 128) {
        float mk = Mk[idx];
        u16 h = f2bf(mk);
        mkT_hi[idx] = h; mkT_lo[idx] = f2bf(mk - bf2f(h));
    }
    {
        int n = idx >> 8, k = idx & 255;
        float wf = Wf[k * DIM + n];
        u16 h = f2bf(wf);
        wfT_hi[idx] = h; wfT_lo[idx] = f2bf(wf - bf2f(h));
    }
    for (int i = idx; i < NUM_C * DIM; i += 32768) ekbf[i] = f2bf(Ek[i]);
    for (int i = idx; i < 2 * NUM_C * DIM; i += 32768) evbf[i] = f2bf(Ev[i]);
}

// ---------------------------------------------------------------------------
// Fused kAB (MFMA, A=bf16-hi only, B=hi+lo). Blocks [0,512): kA role.
// Blocks [512,1024): kB role. 64 rows/block; staging = pure u16 gather.
// f32 outputs (r15/r20 interface).
// ---------------------------------------------------------------------------
__global__ __launch_bounds__(256) void kAB(const int* __restrict__ q,
                                           const int* __restrict__ r,
                                           const u16* __restrict__ ekbf,
                                           const u16* __restrict__ evbf,
                                           const u16* __restrict__ mkT_hi, const u16* __restrict__ mkT_lo,
                                           const u16* __restrict__ weT_hi, const u16* __restrict__ weT_lo,
                                           const u16* __restrict__ waT_hi, const u16* __restrict__ waT_lo,
                                           const float* __restrict__ be, const float* __restrict__ ba,
                                           float* __restrict__ w_out,
                                           float2* __restrict__ ea_out) {
    __shared__ __align__(16) u16 shi[4][16][136];
    __shared__ float slab[4][64];
    const int tid = threadIdx.x;
    const int lane = tid & 63;
    const int wv = tid >> 6;
    const int nloc = lane & 15;
    const int quad = lane >> 4;

    if (blockIdx.x < 512) {
        // ---------------- kA role ----------------
        const int base = blockIdx.x * 64;
        {   // stage k = ekbf[q] (already bf16)
            const int row_l = tid >> 2;
            const int rts = row_l >> 4, ms = row_l & 15;
            const int d0 = (tid & 3) * 32;
            const u16* src = ekbf + (size_t)q[base + row_l] * DIM + d0;
            #pragma unroll
            for (int c8 = 0; c8 < 4; ++c8)
                *reinterpret_cast<bfrag*>(&shi[rts][ms][d0 + c8 * 8]) =
                    *reinterpret_cast<const bfrag*>(src + c8 * 8);
        }
        __syncthreads();

        const int n = wv * 16 + nloc;      // m index
        bfrag Bh[4], Bl[4];
        #pragma unroll
        for (int kc = 0; kc < 4; ++kc) {
            const int ko = kc * 32 + quad * 8;
            Bh[kc] = *reinterpret_cast<const bfrag*>(mkT_hi + n * DIM + ko);
            Bl[kc] = *reinterpret_cast<const bfrag*>(mkT_lo + n * DIM + ko);
        }

        f32x4 acc[4];
        #pragma unroll
        for (int t = 0; t < 4; ++t) acc[t] = 0.f;

        #pragma unroll
        for (int rt = 0; rt < 4; ++rt) {
            #pragma unroll
            for (int kc = 0; kc < 4; ++kc) {
                const int ko = kc * 32 + quad * 8;
                bfrag Ah = *reinterpret_cast<const bfrag*>(&shi[rt][nloc][ko]);
                acc[rt] = __builtin_amdgcn_mfma_f32_16x16x32_bf16(Ah, Bh[kc], acc[rt], 0, 0, 0);
                acc[rt] = __builtin_amdgcn_mfma_f32_16x16x32_bf16(Ah, Bl[kc], acc[rt], 0, 0, 0);
            }
        }

        float ex[4][4];
        #pragma unroll
        for (int rt = 0; rt < 4; ++rt) {
            #pragma unroll
            for (int rg = 0; rg < 4; ++rg) {
                float e = __expf(acc[rt][rg]);
                ex[rt][rg] = e;
                float s = e;
                s += __shfl_xor(s, 1);
                s += __shfl_xor(s, 2);
                s += __shfl_xor(s, 4);
                s += __shfl_xor(s, 8);
                if (nloc == 0) slab[wv][rt * 16 + quad * 4 + rg] = s;
            }
        }
        __syncthreads();

        #pragma unroll
        for (int rt = 0; rt < 4; ++rt) {
            #pragma unroll
            for (int rg = 0; rg < 4; ++rg) {
                const int row = rt * 16 + quad * 4 + rg;
                float tot = slab[0][row] + slab[1][row] + slab[2][row] + slab[3][row];
                w_out[(size_t)(base + row) * MM + n] = ex[rt][rg] / tot;
            }
        }
    } else {
        // ---------------- kB role ----------------
        const int base = (blockIdx.x - 512) * 64;
        {   // stage v = evbf[x] (already bf16)
            const int row_l = tid >> 2;
            const int rts = row_l >> 4, ms = row_l & 15;
            const int d0 = (tid & 3) * 32;
            const int row = base + row_l;
            const int x = q[row] + NUM_C * r[row];
            const u16* src = evbf + (size_t)x * DIM + d0;
            #pragma unroll
            for (int c8 = 0; c8 < 4; ++c8)
                *reinterpret_cast<bfrag*>(&shi[rts][ms][d0 + c8 * 8]) =
                    *reinterpret_cast<const bfrag*>(src + c8 * 8);
        }
        __syncthreads();

        #pragma unroll
        for (int dt = 0; dt < 2; ++dt) {
            const int n = (wv * 2 + dt) * 16 + nloc;
            bfrag Beh[4], Bel[4], Bah[4], Bal[4];
            #pragma unroll
            for (int kc = 0; kc < 4; ++kc) {
                const int ko = kc * 32 + quad * 8;
                Beh[kc] = *reinterpret_cast<const bfrag*>(weT_hi + n * DIM + ko);
                Bel[kc] = *reinterpret_cast<const bfrag*>(weT_lo + n * DIM + ko);
                Bah[kc] = *reinterpret_cast<const bfrag*>(waT_hi + n * DIM + ko);
                Bal[kc] = *reinterpret_cast<const bfrag*>(waT_lo + n * DIM + ko);
            }
            f32x4 acc_e[4], acc_a[4];
            #pragma unroll
            for (int t = 0; t < 4; ++t) { acc_e[t] = 0.f; acc_a[t] = 0.f; }

            #pragma unroll
            for (int rt = 0; rt < 4; ++rt) {
                #pragma unroll
                for (int kc = 0; kc < 4; ++kc) {
                    const int ko = kc * 32 + quad * 8;
                    bfrag Ah = *reinterpret_cast<const bfrag*>(&shi[rt][nloc][ko]);
                    acc_e[rt] = __builtin_amdgcn_mfma_f32_16x16x32_bf16(Ah, Beh[kc], acc_e[rt], 0, 0, 0);
                    acc_a[rt] = __builtin_amdgcn_mfma_f32_16x16x32_bf16(Ah, Bah[kc], acc_a[rt], 0, 0, 0);
                    acc_e[rt] = __builtin_amdgcn_mfma_f32_16x16x32_bf16(Ah, Bel[kc], acc_e[rt], 0, 0, 0);
                    acc_a[rt] = __builtin_amdgcn_mfma_f32_16x16x32_bf16(Ah, Bal[kc], acc_a[rt], 0, 0, 0);
                }
            }
            const float bev = be[n], bav = ba[n];
            #pragma unroll
            for (int rt = 0; rt < 4; ++rt) {
                #pragma unroll
                for (int rg = 0; rg < 4; ++rg) {
                    const int row = base + rt * 16 + quad * 4 + rg;
                    float2 ea;
                    ea.x = sigmoidf_fast(acc_e[rt][rg] + bev);
                    ea.y = tanhf_fast(acc_a[rt][rg] + bav);
                    ea_out[(size_t)row * DIM + n] = ea;
                }
            }
        }
    }
}

// ---------------------------------------------------------------------------
// Kernel C (r25 = r24 asm pipeline + offset-immediates + deferred reduce):
//  - ds_read offsets are now instruction immediates (offset:%c, UU*256 /
//    UU*128 <= 7936 fits 16-bit field): one base VGPR per tile, no per-load
//    v_add (-2 VALU/step, shorter asm chain).
//  - Reduce stages 2-4 + store deferred ONE step via a static `prev` reg
//    (no slot rotation, zero extra instructions): the serial DPP chain of
//    step u executes at step u+1 BEFORE its s_waitcnt, i.e. entirely under
//    the load-wait shadow. Op sequence per element unchanged ->
//    bit-identical numerics. Flush for step 31 after the loop.
//  - Counted lgkmcnt discipline unchanged: WN=6 steady (2 loads/step x
//    4-deep), tail 6/4/2/0; sched_barrier(0) after each wait (rule #18).
// ---------------------------------------------------------------------------
__device__ __forceinline__ void scan32(u32 wbase, u32 ebase,
                                       int t0, int p,
                                       float (&Mv)[4], float* rp) {
    float4 wq[4];
    float2 eq[4];

#define KC_LOAD(SLOT, UU)                                                     \
    asm volatile("ds_read_b128 %0, %1 offset:%c2"                             \
                 : "=v"(wq[SLOT]) : "v"(wbase), "i"((UU) * 256));             \
    asm volatile("ds_read_b64 %0, %1 offset:%c2"                              \
                 : "=v"(eq[SLOT]) : "v"(ebase), "i"((UU) * 128));

    KC_LOAD(0, 0) KC_LOAD(1, 1) KC_LOAD(2, 2) KC_LOAD(3, 3)

    float prev = 0.f;

#define KC_STEP(UU, WN) {                                                     \
    if ((UU) >= 1) {      /* finish step UU-1 under the load-wait shadow */   \
        float f = prev;                                                       \
        f += quad_swap2(f);                                                   \
        f += row_ror4(f);                                                     \
        f += row_ror8(f);                                                     \
        if (p == 0) rp[(size_t)(t0 + (UU) - 1) * DIM] = f;                    \
    }                                                                         \
    asm volatile("s_waitcnt lgkmcnt(" #WN ")");                               \
    __builtin_amdgcn_sched_barrier(0);                                        \
    float4 w4 = wq[(UU) & 3];                                                 \
    float2 ea = eq[(UU) & 3];                                                 \
    if ((UU) + 4 < 32) { KC_LOAD((UU) & 3, (UU) + 4) }                        \
    float e_c = ea.x, a_c = ea.y;                                             \
    float o0 = Mv[0], o1 = Mv[1], o2 = Mv[2], o3 = Mv[3];                     \
    float pp0 = w4.x * o0;                                                    \
    pp0 = fmaf(w4.y, o1, pp0);                                                \
    float pp1 = w4.z * o2;                                                    \
    pp1 = fmaf(w4.w, o3, pp1);                                                \
    Mv[0] = fmaf(w4.x, fmaf(-o0, e_c, a_c), o0);                              \
    Mv[1] = fmaf(w4.y, fmaf(-o1, e_c, a_c), o1);                              \
    Mv[2] = fmaf(w4.z, fmaf(-o2, e_c, a_c), o2);                              \
    Mv[3] = fmaf(w4.w, fmaf(-o3, e_c, a_c), o3);                              \
    float part = pp0 + pp1;                                                   \
    part += quad_swap1(part);   /* stage 1 only; rest next step */            \
    prev = part; }

    KC_STEP(0, 6)  KC_STEP(1, 6)  KC_STEP(2, 6)  KC_STEP(3, 6)
    KC_STEP(4, 6)  KC_STEP(5, 6)  KC_STEP(6, 6)  KC_STEP(7, 6)
    KC_STEP(8, 6)  KC_STEP(9, 6)  KC_STEP(10, 6) KC_STEP(11, 6)
    KC_STEP(12, 6) KC_STEP(13, 6) KC_STEP(14, 6) KC_STEP(15, 6)
    KC_STEP(16, 6) KC_STEP(17, 6) KC_STEP(18, 6) KC_STEP(19, 6)
    KC_STEP(20, 6) KC_STEP(21, 6) KC_STEP(22, 6) KC_STEP(23, 6)
    KC_STEP(24, 6) KC_STEP(25, 6) KC_STEP(26, 6) KC_STEP(27, 6)
    KC_STEP(28, 6) KC_STEP(29, 4) KC_STEP(30, 2) KC_STEP(31, 0)

    {   // flush step 31: stages 2-4 + store
        float f = prev;
        f += quad_swap2(f);
        f += row_ror4(f);
        f += row_ror8(f);
        if (p == 0) rp[(size_t)(t0 + 31) * DIM] = f;
    }
#undef KC_STEP
#undef KC_LOAD
}

__global__ __launch_bounds__(256) void kC(const float* __restrict__ Mv0,
                                          const float* __restrict__ w_in,
                                          const float2* __restrict__ ea_in,
                                          float* __restrict__ rd) {
    __shared__ __align__(16) float  wlds[2][32][64];    // 16 KB
    __shared__ __align__(16) float2 ealds[2][32][16];   // 8 KB
    const int tid = threadIdx.x;
    const int p  = tid & 15;          // m-group 0..15
    const int dl = tid >> 4;          // d within slice 0..15
    const int ds = blockIdx.x;        // d-chunk 0..7
    const int b  = blockIdx.y;        // batch
    const int d  = ds * 16 + dl;
    const int m0 = p * 4;

    const char* wsrc  = (const char*)(w_in + (size_t)b * LL * MM);
    const char* easrc = (const char*)(ea_in + (size_t)b * LL * DIM + ds * 16);
    float* rp = rd + (size_t)b * LL * DIM + d;

    auto dma = [&](int c, int bufi) {
        const char* wt = wsrc + (size_t)c * 8192;         // w tile: 32x64 f32 = 8 KB
        char* wl = (char*)&wlds[bufi][0][0];
        const int off = tid * 16;                         // 0..4095
        ld16(wt + off, wl + off);
        ld16(wt + 4096 + off, wl + 4096 + off);
        // ea tile: 32 rows x 16 d x 8 B = 4 KB; 128 B per row, 8 lanes/row
        const int tl = tid >> 3, wi = (tid & 7) * 16;
        ld16(easrc + (size_t)(c * 32 + tl) * (DIM * 8) + wi,
             (char*)&ealds[bufi][0][0] + tid * 16);
    };

    dma(0, 0);

    float Mv[4];
    #pragma unroll
    for (int j = 0; j < 4; ++j)
        Mv[j] = Mv0[(m0 + j) * DIM + d];

    __builtin_amdgcn_s_waitcnt(0x0F70);   // vmcnt(0): tile-0 DMA + Mv loads done
    __syncthreads();

    int buf = 0;
    for (int c = 0; c < LL / 32; ++c) {
        if (c + 1 < LL / 32) dma(c + 1, buf ^ 1);
        {
            u32 wbase = (u32)(size_t)(__attribute__((address_space(3))) float*)&wlds[buf][0][0]
                        + (u32)m0 * 4u;
            u32 ebase = (u32)(size_t)(__attribute__((address_space(3))) float2*)&ealds[buf][0][0]
                        + (u32)dl * 8u;
            scan32(wbase, ebase, c * 32, p, Mv, rp);
        }
        if (c + 1 < LL / 32) {
            __builtin_amdgcn_s_waitcnt(0x8F70);   // vmcnt(32): DMAs retired, stores may fly
            __syncthreads();
            buf ^= 1;
        }
    }
}

// ---------------------------------------------------------------------------
// Kernel D (MFMA, A=hi only): f = tanh([rd,k]@Wf+bf); p = sigmoid(f@Wp+bp).
// 64 rows/block; rd staged via f2bf (hi), Ek gathered pre-converted.
// ---------------------------------------------------------------------------
__global__ __launch_bounds__(256) void kD(const int* __restrict__ q,
                                          const u16* __restrict__ ekbf,
                                          const u16* __restrict__ wfT_hi, const u16* __restrict__ wfT_lo,
                                          const float* __restrict__ bfv,
                                          const float* __restrict__ Wp, const float* __restrict__ bp,
                                          const float* __restrict__ rd,
                                          float* __restrict__ out) {
    __shared__ __align__(16) u16 xhi[4][16][264];   // 33792 B (fbuf overlays exactly)
    __shared__ float sred[64][4];
    const int tid = threadIdx.x;
    const int base = blockIdx.x * 64;
    const int row_l = tid >> 2;
    const int rts = row_l >> 4, ms = row_l & 15;
    const int d0 = (tid & 3) * 32;
    const int row = base + row_l;

    {   // x[:, 0:128) = rd -> bf16 hi
        const float* src = rd + (size_t)row * DIM + d0;
        #pragma unroll
        for (int c8 = 0; c8 < 4; ++c8) {
            float4 f0 = *reinterpret_cast<const float4*>(src + c8 * 8);
            float4 f1 = *reinterpret_cast<const float4*>(src + c8 * 8 + 4);
            float xs[8] = {f0.x, f0.y, f0.z, f0.w, f1.x, f1.y, f1.z, f1.w};
            bfrag h;
            #pragma unroll
            for (int j = 0; j < 8; ++j) h[j] = (short)f2bf(xs[j]);
            *reinterpret_cast<bfrag*>(&xhi[rts][ms][d0 + c8 * 8]) = h;
        }
    }
    {   // x[:, 128:256) = ekbf[q[row]] (already bf16)
        const u16* src = ekbf + (size_t)q[row] * DIM + d0;
        #pragma unroll
        for (int c8 = 0; c8 < 4; ++c8)
            *reinterpret_cast<bfrag*>(&xhi[rts][ms][128 + d0 + c8 * 8]) =
                *reinterpret_cast<const bfrag*>(src + c8 * 8);
    }
    __syncthreads();

    const int lane = tid & 63;
    const int wv = tid >> 6;
    const int nloc = lane & 15;
    const int quad = lane >> 4;
    float* fbuf = reinterpret_cast<float*>(&xhi[0][0][0]);   // overlay after sync

    f32x4 acc[2][4];
    #pragma unroll
    for (int dt = 0; dt < 2; ++dt)
        #pragma unroll
        for (int t = 0; t < 4; ++t) acc[dt][t] = 0.f;

    #pragma unroll
    for (int dt = 0; dt < 2; ++dt) {
        const int n = (wv * 2 + dt) * 16 + nloc;
        bfrag Bh[8], Bl[8];
        #pragma unroll
        for (int kc = 0; kc < 8; ++kc) {
            const int ko = kc * 32 + quad * 8;
            Bh[kc] = *reinterpret_cast<const bfrag*>(wfT_hi + n * 256 + ko);
            Bl[kc] = *reinterpret_cast<const bfrag*>(wfT_lo + n * 256 + ko);
        }
        #pragma unroll
        for (int rt = 0; rt < 4; ++rt) {
            #pragma unroll
            for (int kc = 0; kc < 8; ++kc) {
                const int ko = kc * 32 + quad * 8;
                bfrag Ah = *reinterpret_cast<const bfrag*>(&xhi[rt][nloc][ko]);
                acc[dt][rt] = __builtin_amdgcn_mfma_f32_16x16x32_bf16(Ah, Bh[kc], acc[dt][rt], 0, 0, 0);
                acc[dt][rt] = __builtin_amdgcn_mfma_f32_16x16x32_bf16(Ah, Bl[kc], acc[dt][rt], 0, 0, 0);
            }
        }
    }
    __syncthreads();   // LDS x reads done before fbuf overlay

    #pragma unroll
    for (int dt = 0; dt < 2; ++dt) {
        const int n = (wv * 2 + dt) * 16 + nloc;
        const float bfn = bfv[n], wpn = Wp[n];
        #pragma unroll
        for (int rt = 0; rt < 4; ++rt)
            #pragma unroll
            for (int rg = 0; rg < 4; ++rg)
                fbuf[(rt * 16 + quad * 4 + rg) * 132 + n] = tanhf_fast(acc[dt][rt][rg] + bfn) * wpn;
    }
    __syncthreads();

    {
        float s = 0.f;
        const int c = tid & 3;
        #pragma unroll
        for (int k = 0; k < 32; ++k) s += fbuf[row_l * 132 + c * 32 + k];
        sred[row_l][c] = s;
    }
    __syncthreads();
    if (tid < 64)
        out[base + tid] = sigmoidf_fast(sred[tid][0] + sred[tid][1] + sred[tid][2] + sred[tid][3] + bp[0]);
}

// ---------------------------------------------------------------------------
extern "C" void kernel_launch(void* const* d_in, const int* in_sizes, int n_in,
                              void* d_out, int out_size, void* d_ws, size_t ws_size,
                              hipStream_t stream) {
    const int*   q   = (const int*)d_in[0];
    const int*   r   = (const int*)d_in[1];
    const float* Ek  = (const float*)d_in[2];
    const float* Ev  = (const float*)d_in[3];
    const float* Mk  = (const float*)d_in[4];
    const float* Mv0 = (const float*)d_in[5];
    const float* We  = (const float*)d_in[6];
    const float* be  = (const float*)d_in[7];
    const float* Wa  = (const float*)d_in[8];
    const float* ba  = (const float*)d_in[9];
    const float* Wf  = (const float*)d_in[10];
    const float* bfv = (const float*)d_in[11];
    const float* Wp  = (const float*)d_in[12];
    const float* bp  = (const float*)d_in[13];
    float* out = (float*)d_out;

    float*  ws     = (float*)d_ws;
    float*  w_buf  = ws;                                      // 8 MB
    float2* ea_buf = (float2*)(w_buf + (size_t)NROWS * MM);   // 32 MB
    float*  rd     = (float*)(ea_buf + (size_t)NROWS * DIM);  // 16 MB

    // prepped bf16 data right after rd (~1.1 MB)
    u16* weT_hi = (u16*)(rd + (size_t)NROWS * DIM);
    u16* weT_lo = weT_hi + 16384;
    u16* waT_hi = weT_lo + 16384;
    u16* waT_lo = waT_hi + 16384;
    u16* wfT_hi = waT_lo + 16384;
    u16* wfT_lo = wfT_hi + 32768;
    u16* mkT_hi = wfT_lo + 32768;
    u16* mkT_lo = mkT_hi + 8192;
    u16* ekbf   = mkT_lo + 8192;      // 128000 u16
    u16* evbf   = ekbf + 128000;      // 256000 u16

    kP<<<dim3(128), 256, 0, stream>>>(We, Wa, Wf, Mk, Ek, Ev,
                                      weT_hi, weT_lo, waT_hi, waT_lo,
                                      wfT_hi, wfT_lo, mkT_hi, mkT_lo, ekbf, evbf);
    kAB<<<dim3(1024), 256, 0, stream>>>(q, r, ekbf, evbf, mkT_hi, mkT_lo,
                                        weT_hi, weT_lo, waT_hi, waT_lo,
                                        be, ba, w_buf, ea_buf);
    kC<<<dim3(8, BB), 256, 0, stream>>>(Mv0, w_buf, ea_buf, rd);
    kD<<<dim3(NROWS / 64), 256, 0, stream>>>(q, ekbf, wfT_hi, wfT_lo, bfv, Wp, bp, rd, out);
}